// Round 1
// baseline (2876.605 us; speedup 1.0000x reference)
//
#include <hip/hip_runtime.h>

#define N_NODES 50000
#define N_EDGES 800000
#define IN_F 64
#define H_F 128

static __device__ __forceinline__ float4 ld4(const float* p) {
    return *reinterpret_cast<const float4*>(p);
}
static __device__ __forceinline__ void st4(float* p, float4 v) {
    *reinterpret_cast<float4*>(p) = v;
}

// -------------------- x = features * mask --------------------
__global__ __launch_bounds__(256) void mul_mask_k(const float* __restrict__ a,
                                                  const float* __restrict__ b,
                                                  float* __restrict__ o, int n4) {
    int i = blockIdx.x * 256 + threadIdx.x;
    if (i < n4) {
        float4 x = ld4(a + 4 * i);
        float4 m = ld4(b + 4 * i);
        float4 r;
        r.x = x.x * m.x; r.y = x.y * m.y; r.z = x.z * m.z; r.w = x.w * m.w;
        st4(o + 4 * i, r);
    }
}

// -------------------- tiled fp32 GEMM: out[n][c] = rs_out[n] * sum_k A'[n][k]*W[k][c]
// MODE 0: A' = A
// MODE 1: A' = relu(A * rs_in[n] + bias_in[k])      (fused GCL activation)
// Block: 256 threads, 64 nodes/block. Thread (tr=tid&15, tc=tid>>4) computes
// nodes 4*tr..4*tr+3 x cols tc*CPT..tc*CPT+CPT-1.  Weight fully in LDS.
template<int K, int N, int MODE>
__global__ __launch_bounds__(256) void gemm_k(
    const float* __restrict__ A, const float* __restrict__ W,
    const float* __restrict__ bias_in, const float* __restrict__ rs_in,
    const float* __restrict__ rs_out, float* __restrict__ out, int M)
{
    constexpr int CPT = N / 16;     // cols per thread (8 or 4)
    constexpr int AS  = K + 1;      // padded LDS stride for A tile
    constexpr int KQ  = K / 4;
    __shared__ __align__(16) float Wl[K * N];
    __shared__ __align__(16) float Al[64 * AS];

    const int tid = threadIdx.x;
    const int n0  = blockIdx.x << 6;

    // stage weights (vectorized, coalesced)
    for (int i = tid; i < K * N / 4; i += 256) {
        st4(&Wl[4 * i], ld4(W + 4 * i));
    }
    // stage A tile (row-major, +1 padded stride -> conflict-free col reads)
    for (int i4 = tid; i4 < 64 * KQ; i4 += 256) {
        int n  = i4 / KQ;                 // KQ is a power of 2 -> shift
        int k4 = (i4 & (KQ - 1)) << 2;
        int gn = n0 + n;
        float4 v = make_float4(0.f, 0.f, 0.f, 0.f);
        if (gn < M) {
            v = ld4(A + gn * K + k4);
            if (MODE == 1) {
                float r   = rs_in[gn];
                float4 b4 = ld4(bias_in + k4);
                v.x = fmaxf(fmaf(v.x, r, b4.x), 0.f);
                v.y = fmaxf(fmaf(v.y, r, b4.y), 0.f);
                v.z = fmaxf(fmaf(v.z, r, b4.z), 0.f);
                v.w = fmaxf(fmaf(v.w, r, b4.w), 0.f);
            }
        }
        float* p = &Al[n * AS + k4];
        p[0] = v.x; p[1] = v.y; p[2] = v.z; p[3] = v.w;
    }
    __syncthreads();

    const int tr = tid & 15;
    const int tc = tid >> 4;

    float acc[4][CPT];
#pragma unroll
    for (int i = 0; i < 4; ++i)
#pragma unroll
        for (int j = 0; j < CPT; ++j) acc[i][j] = 0.f;

#pragma unroll 4
    for (int k = 0; k < K; ++k) {
        float a0 = Al[(4 * tr + 0) * AS + k];
        float a1 = Al[(4 * tr + 1) * AS + k];
        float a2 = Al[(4 * tr + 2) * AS + k];
        float a3 = Al[(4 * tr + 3) * AS + k];
#pragma unroll
        for (int jq = 0; jq < CPT / 4; ++jq) {
            float4 w = ld4(&Wl[k * N + tc * CPT + 4 * jq]);
            acc[0][4 * jq + 0] += a0 * w.x; acc[0][4 * jq + 1] += a0 * w.y;
            acc[0][4 * jq + 2] += a0 * w.z; acc[0][4 * jq + 3] += a0 * w.w;
            acc[1][4 * jq + 0] += a1 * w.x; acc[1][4 * jq + 1] += a1 * w.y;
            acc[1][4 * jq + 2] += a1 * w.z; acc[1][4 * jq + 3] += a1 * w.w;
            acc[2][4 * jq + 0] += a2 * w.x; acc[2][4 * jq + 1] += a2 * w.y;
            acc[2][4 * jq + 2] += a2 * w.z; acc[2][4 * jq + 3] += a2 * w.w;
            acc[3][4 * jq + 0] += a3 * w.x; acc[3][4 * jq + 1] += a3 * w.y;
            acc[3][4 * jq + 2] += a3 * w.z; acc[3][4 * jq + 3] += a3 * w.w;
        }
    }

#pragma unroll
    for (int i = 0; i < 4; ++i) {
        int gn = n0 + 4 * tr + i;
        if (gn >= M) continue;
        float s = rs_out[gn];
#pragma unroll
        for (int jq = 0; jq < CPT / 4; ++jq) {
            float4 o;
            o.x = acc[i][4 * jq + 0] * s; o.y = acc[i][4 * jq + 1] * s;
            o.z = acc[i][4 * jq + 2] * s; o.w = acc[i][4 * jq + 3] * s;
            st4(out + gn * N + tc * CPT + 4 * jq, o);
        }
    }
}

// -------------------- edge scatter-add: acc[dst] += feat[src] --------------------
// one thread per (edge, 4-feature chunk); float4 gather + 4 atomics
template<int LOGF>
__global__ __launch_bounds__(256) void edge_agg_k(const float* __restrict__ feat,
        const int* __restrict__ src, const int* __restrict__ dst,
        float* __restrict__ acc, int nE) {
    constexpr int FQ = 1 << (LOGF - 2);
    int i = blockIdx.x * 256 + threadIdx.x;
    int total = nE * FQ;
    if (i >= total) return;
    int e  = i >> (LOGF - 2);
    int cq = (i & (FQ - 1)) << 2;
    int s = src[e], d = dst[e];
    float4 v = ld4(feat + (s << LOGF) + cq);
    float* ap = acc + (d << LOGF) + cq;
    atomicAdd(ap + 0, v.x);
    atomicAdd(ap + 1, v.y);
    atomicAdd(ap + 2, v.z);
    atomicAdd(ap + 3, v.w);
}

// -------------------- out = sigmoid(hb*ng + bh + sb*nf + bs) --------------------
__global__ __launch_bounds__(256) void final_k(const float* __restrict__ hb,
        const float* __restrict__ sb, const float* __restrict__ ng,
        const float* __restrict__ nf, const float* __restrict__ bh,
        const float* __restrict__ bs, float* __restrict__ out) {
    int i = blockIdx.x * 256 + threadIdx.x;
    int total4 = N_NODES * (IN_F / 4);
    if (i >= total4) return;
    int n  = i >> 4;
    int cq = (i & 15) << 2;
    float g = ng[n], f = nf[n];
    float4 a  = ld4(hb + n * IN_F + cq);
    float4 b  = ld4(sb + n * IN_F + cq);
    float4 b4 = ld4(bh + cq);
    float4 s4 = ld4(bs + cq);
    float4 o;
    float t;
    t = a.x * g + b4.x + b.x * f + s4.x; o.x = 1.f / (1.f + expf(-t));
    t = a.y * g + b4.y + b.y * f + s4.y; o.y = 1.f / (1.f + expf(-t));
    t = a.z * g + b4.z + b.z * f + s4.z; o.z = 1.f / (1.f + expf(-t));
    t = a.w * g + b4.w + b.w * f + s4.w; o.w = 1.f / (1.f + expf(-t));
    st4(out + n * IN_F + cq, o);
}

extern "C" void kernel_launch(void* const* d_in, const int* in_sizes, int n_in,
                              void* d_out, int out_size, void* d_ws, size_t ws_size,
                              hipStream_t stream) {
    const float* features = (const float*)d_in[0];
    const float* mask     = (const float*)d_in[1];
    const float* norm_g   = (const float*)d_in[2];
    const float* norm_f   = (const float*)d_in[3];
    const int*   src_g    = (const int*)d_in[4];
    const int*   dst_g    = (const int*)d_in[5];
    const int*   src_f    = (const int*)d_in[6];
    const int*   dst_f    = (const int*)d_in[7];
    const float* W1  = (const float*)d_in[8];
    const float* b1  = (const float*)d_in[9];
    const float* wh  = (const float*)d_in[10];
    const float* bh  = (const float*)d_in[11];
    const float* wsw = (const float*)d_in[12];
    const float* bs  = (const float*)d_in[13];
    float* out = (float*)d_out;
    float* ws  = (float*)d_ws;

    // workspace layout (floats), with lifetime-based aliasing; total 64 MB
    float* x    = ws;               // [50000*64]   live: whole run
    float* h1   = ws + 3200000;     // [50000*128]  live: G1..agg1
    float* hagg = ws + 9600000;     // [50000*128]  live: agg1..G2
    float* hb0  = ws + 3200000;     // [50000*64]   alias h1 (dead after agg1)
    float* sb0  = ws + 6400000;     // [50000*64]   alias h1 upper half
    float* hbag = ws + 9600000;     // [50000*64]   alias hagg (dead after G2)
    float* sbag = ws + 12800000;    // [50000*64]

    int gblocks = (N_NODES + 63) / 64;   // 782

    // 1. x = features * mask
    int n4 = N_NODES * IN_F / 4;
    mul_mask_k<<<(n4 + 255) / 256, 256, 0, stream>>>(features, mask, x, n4);

    // 2. h1 = (x @ W1) * norm_g
    gemm_k<64, 128, 0><<<gblocks, 256, 0, stream>>>(x, W1, nullptr, nullptr,
                                                    norm_g, h1, N_NODES);

    // 3-4. hagg = segment_sum(h1[src_g] -> dst_g)
    hipMemsetAsync(hagg, 0, (size_t)N_NODES * H_F * sizeof(float), stream);
    int tot1 = N_EDGES * (H_F / 4);
    edge_agg_k<7><<<(tot1 + 255) / 256, 256, 0, stream>>>(h1, src_g, dst_g, hagg, N_EDGES);

    // 5. hb0 = (relu(hagg*ng + b1) @ wh) * ng      (relu fused into staging)
    gemm_k<128, 64, 1><<<gblocks, 256, 0, stream>>>(hagg, wh, b1, norm_g,
                                                    norm_g, hb0, N_NODES);
    // 6. sb0 = (x @ ws) * nf
    gemm_k<64, 64, 0><<<gblocks, 256, 0, stream>>>(x, wsw, nullptr, nullptr,
                                                   norm_f, sb0, N_NODES);

    // 7-9. two 64-wide aggregations
    hipMemsetAsync(hbag, 0, (size_t)2 * N_NODES * IN_F * sizeof(float), stream);
    int tot2 = N_EDGES * (IN_F / 4);
    edge_agg_k<6><<<(tot2 + 255) / 256, 256, 0, stream>>>(hb0, src_g, dst_g, hbag, N_EDGES);
    edge_agg_k<6><<<(tot2 + 255) / 256, 256, 0, stream>>>(sb0, src_f, dst_f, sbag, N_EDGES);

    // 10. out = sigmoid(hbag*ng + bh + sbag*nf + bs)
    final_k<<<(N_NODES * 16 + 255) / 256, 256, 0, stream>>>(hbag, sbag, norm_g,
                                                            norm_f, bh, bs, out);
}

// Round 2
// 706.072 us; speedup vs baseline: 4.0741x; 4.0741x over previous
//
#include <hip/hip_runtime.h>

#define N_NODES 50000
#define N_EDGES 800000
#define IN_F 64
#define H_F 128

typedef unsigned short u16;

static __device__ __forceinline__ float4 ld4(const float* p) {
    return *reinterpret_cast<const float4*>(p);
}
static __device__ __forceinline__ void st4(float* p, float4 v) {
    *reinterpret_cast<float4*>(p) = v;
}
static __device__ __forceinline__ float2 ld2(const float* p) {
    return *reinterpret_cast<const float2*>(p);
}

// -------------------- x = features * mask --------------------
__global__ __launch_bounds__(256) void mul_mask_k(const float* __restrict__ a,
                                                  const float* __restrict__ b,
                                                  float* __restrict__ o, int n4) {
    int i = blockIdx.x * 256 + threadIdx.x;
    if (i < n4) {
        float4 x = ld4(a + 4 * i);
        float4 m = ld4(b + 4 * i);
        float4 r;
        r.x = x.x * m.x; r.y = x.y * m.y; r.z = x.z * m.z; r.w = x.w * m.w;
        st4(o + 4 * i, r);
    }
}

// -------------------- CSR build: histogram / scan / scatter --------------------
__global__ __launch_bounds__(256) void hist_k(const int* __restrict__ dst,
                                              int* __restrict__ deg, int nE) {
    int i = blockIdx.x * 256 + threadIdx.x;
    if (i < nE) atomicAdd(&deg[dst[i]], 1);
}

// single-block exclusive scan of deg[0..n) -> rowptr[0..n], also copies into cur
__global__ __launch_bounds__(1024) void scan_k(const int* __restrict__ deg,
                                               int* __restrict__ rowptr,
                                               int* __restrict__ cur, int n) {
    __shared__ int part[1024];
    const int tid = threadIdx.x;
    const int chunk = (n + 1023) / 1024;
    const int lo = tid * chunk;
    const int hi = min(lo + chunk, n);
    int s = 0;
    for (int i = lo; i < hi; ++i) s += deg[i];
    part[tid] = s;
    __syncthreads();
    for (int off = 1; off < 1024; off <<= 1) {
        int v = (tid >= off) ? part[tid - off] : 0;
        __syncthreads();
        part[tid] += v;
        __syncthreads();
    }
    int ex = (tid == 0) ? 0 : part[tid - 1];
    for (int i = lo; i < hi; ++i) {
        rowptr[i] = ex;
        cur[i] = ex;
        ex += deg[i];
    }
    if (tid == 1023) rowptr[n] = ex;   // == total (tail chunks contribute 0)
}

__global__ __launch_bounds__(256) void scatter_k(const int* __restrict__ src,
                                                 const int* __restrict__ dst,
                                                 int* __restrict__ cur,
                                                 u16* __restrict__ adj, int nE) {
    int i = blockIdx.x * 256 + threadIdx.x;
    if (i < nE) {
        int p = atomicAdd(&cur[dst[i]], 1);
        adj[p] = (u16)src[i];
    }
}

// -------------------- tiled fp32 GEMM: out[n][c] = rs_out[n] * sum_k A[n][k]*W[k][c]
template<int K, int N>
__global__ __launch_bounds__(256) void gemm_k(
    const float* __restrict__ A, const float* __restrict__ W,
    const float* __restrict__ rs_out, float* __restrict__ out, int M)
{
    constexpr int CPT = N / 16;
    constexpr int AS  = K + 1;
    constexpr int KQ  = K / 4;
    __shared__ __align__(16) float Wl[K * N];
    __shared__ __align__(16) float Al[64 * AS];

    const int tid = threadIdx.x;
    const int n0  = blockIdx.x << 6;

    for (int i = tid; i < K * N / 4; i += 256) st4(&Wl[4 * i], ld4(W + 4 * i));
    for (int i4 = tid; i4 < 64 * KQ; i4 += 256) {
        int n  = i4 / KQ;
        int k4 = (i4 & (KQ - 1)) << 2;
        int gn = n0 + n;
        float4 v = make_float4(0.f, 0.f, 0.f, 0.f);
        if (gn < M) v = ld4(A + gn * K + k4);
        float* p = &Al[n * AS + k4];
        p[0] = v.x; p[1] = v.y; p[2] = v.z; p[3] = v.w;
    }
    __syncthreads();

    const int tr = tid & 15;
    const int tc = tid >> 4;

    float acc[4][CPT];
#pragma unroll
    for (int i = 0; i < 4; ++i)
#pragma unroll
        for (int j = 0; j < CPT; ++j) acc[i][j] = 0.f;

#pragma unroll 4
    for (int k = 0; k < K; ++k) {
        float a0 = Al[(4 * tr + 0) * AS + k];
        float a1 = Al[(4 * tr + 1) * AS + k];
        float a2 = Al[(4 * tr + 2) * AS + k];
        float a3 = Al[(4 * tr + 3) * AS + k];
#pragma unroll
        for (int jq = 0; jq < CPT / 4; ++jq) {
            float4 w = ld4(&Wl[k * N + tc * CPT + 4 * jq]);
            acc[0][4 * jq + 0] += a0 * w.x; acc[0][4 * jq + 1] += a0 * w.y;
            acc[0][4 * jq + 2] += a0 * w.z; acc[0][4 * jq + 3] += a0 * w.w;
            acc[1][4 * jq + 0] += a1 * w.x; acc[1][4 * jq + 1] += a1 * w.y;
            acc[1][4 * jq + 2] += a1 * w.z; acc[1][4 * jq + 3] += a1 * w.w;
            acc[2][4 * jq + 0] += a2 * w.x; acc[2][4 * jq + 1] += a2 * w.y;
            acc[2][4 * jq + 2] += a2 * w.z; acc[2][4 * jq + 3] += a2 * w.w;
            acc[3][4 * jq + 0] += a3 * w.x; acc[3][4 * jq + 1] += a3 * w.y;
            acc[3][4 * jq + 2] += a3 * w.z; acc[3][4 * jq + 3] += a3 * w.w;
        }
    }

#pragma unroll
    for (int i = 0; i < 4; ++i) {
        int gn = n0 + 4 * tr + i;
        if (gn >= M) continue;
        float s = rs_out[gn];
#pragma unroll
        for (int jq = 0; jq < CPT / 4; ++jq) {
            float4 o;
            o.x = acc[i][4 * jq + 0] * s; o.y = acc[i][4 * jq + 1] * s;
            o.z = acc[i][4 * jq + 2] * s; o.w = acc[i][4 * jq + 3] * s;
            st4(out + gn * N + tc * CPT + 4 * jq, o);
        }
    }
}

// -------------------- fused: hb0[n] = ng[n] * (relu(aggG(h1)[n]*ng[n] + b1) @ wh)
// one wave per node; v (128) held 2 floats/lane; wh (128x64) in LDS;
// mat-vec via readlane broadcast (full unroll -> constant lane index).
__global__ __launch_bounds__(256) void agg_matvec_k(
    const float* __restrict__ h1, const int* __restrict__ rowptr,
    const u16* __restrict__ adj, const float* __restrict__ ng,
    const float* __restrict__ b1, const float* __restrict__ wh,
    float* __restrict__ out)
{
    __shared__ __align__(16) float whL[H_F * IN_F];   // 32 KB
    const int tid = threadIdx.x;
    for (int i = tid; i < H_F * IN_F / 4; i += 256) st4(&whL[4 * i], ld4(wh + 4 * i));
    __syncthreads();

    const int wv = tid >> 6, lane = tid & 63;
    const int nwaves = gridDim.x * 4;

    for (int n = blockIdx.x * 4 + wv; n < N_NODES; n += nwaves) {
        const int e1 = rowptr[n + 1];
        int e = rowptr[n];
        float2 acc = make_float2(0.f, 0.f);
        for (; e + 4 <= e1; e += 4) {
            int s0 = adj[e], s1 = adj[e + 1], s2 = adj[e + 2], s3 = adj[e + 3];
            float2 a0 = ld2(h1 + s0 * H_F + 2 * lane);
            float2 a1 = ld2(h1 + s1 * H_F + 2 * lane);
            float2 a2 = ld2(h1 + s2 * H_F + 2 * lane);
            float2 a3 = ld2(h1 + s3 * H_F + 2 * lane);
            acc.x += (a0.x + a1.x) + (a2.x + a3.x);
            acc.y += (a0.y + a1.y) + (a2.y + a3.y);
        }
        for (; e < e1; ++e) {
            float2 a = ld2(h1 + adj[e] * H_F + 2 * lane);
            acc.x += a.x; acc.y += a.y;
        }
        const float r = ng[n];
        const float v0 = fmaxf(fmaf(acc.x, r, b1[2 * lane]), 0.f);
        const float v1 = fmaxf(fmaf(acc.y, r, b1[2 * lane + 1]), 0.f);

        float o = 0.f;
#pragma unroll
        for (int l = 0; l < 64; ++l) {
            float a = __shfl(v0, l);            // v[2l]   -> readlane const
            float b = __shfl(v1, l);            // v[2l+1]
            o = fmaf(a, whL[(2 * l) * IN_F + lane], o);
            o = fmaf(b, whL[(2 * l + 1) * IN_F + lane], o);
        }
        out[n * IN_F + lane] = o * r;
    }
}

// -------------------- fused final: two 64-wide CSR aggs + bias + sigmoid ----
__global__ __launch_bounds__(256) void final_agg_k(
    const float* __restrict__ hb, const float* __restrict__ sb,
    const int* __restrict__ rp_g, const u16* __restrict__ adj_g,
    const int* __restrict__ rp_f, const u16* __restrict__ adj_f,
    const float* __restrict__ ng, const float* __restrict__ nf,
    const float* __restrict__ bh, const float* __restrict__ bs,
    float* __restrict__ out)
{
    const int wv = threadIdx.x >> 6, lane = threadIdx.x & 63;
    const int n = blockIdx.x * 4 + wv;
    if (n >= N_NODES) return;

    float accg = 0.f;
    {
        const int e1 = rp_g[n + 1];
        int e = rp_g[n];
        for (; e + 4 <= e1; e += 4) {
            int s0 = adj_g[e], s1 = adj_g[e + 1], s2 = adj_g[e + 2], s3 = adj_g[e + 3];
            float a0 = hb[s0 * IN_F + lane];
            float a1 = hb[s1 * IN_F + lane];
            float a2 = hb[s2 * IN_F + lane];
            float a3 = hb[s3 * IN_F + lane];
            accg += (a0 + a1) + (a2 + a3);
        }
        for (; e < e1; ++e) accg += hb[adj_g[e] * IN_F + lane];
    }
    float accf = 0.f;
    {
        const int e1 = rp_f[n + 1];
        int e = rp_f[n];
        for (; e + 4 <= e1; e += 4) {
            int s0 = adj_f[e], s1 = adj_f[e + 1], s2 = adj_f[e + 2], s3 = adj_f[e + 3];
            float a0 = sb[s0 * IN_F + lane];
            float a1 = sb[s1 * IN_F + lane];
            float a2 = sb[s2 * IN_F + lane];
            float a3 = sb[s3 * IN_F + lane];
            accf += (a0 + a1) + (a2 + a3);
        }
        for (; e < e1; ++e) accf += sb[adj_f[e] * IN_F + lane];
    }
    float t = accg * ng[n] + bh[lane] + accf * nf[n] + bs[lane];
    out[n * IN_F + lane] = 1.f / (1.f + expf(-t));
}

extern "C" void kernel_launch(void* const* d_in, const int* in_sizes, int n_in,
                              void* d_out, int out_size, void* d_ws, size_t ws_size,
                              hipStream_t stream) {
    const float* features = (const float*)d_in[0];
    const float* mask     = (const float*)d_in[1];
    const float* norm_g   = (const float*)d_in[2];
    const float* norm_f   = (const float*)d_in[3];
    const int*   src_g    = (const int*)d_in[4];
    const int*   dst_g    = (const int*)d_in[5];
    const int*   src_f    = (const int*)d_in[6];
    const int*   dst_f    = (const int*)d_in[7];
    const float* W1  = (const float*)d_in[8];
    const float* b1  = (const float*)d_in[9];
    const float* wh  = (const float*)d_in[10];
    const float* bh  = (const float*)d_in[11];
    const float* wsw = (const float*)d_in[12];
    const float* bs  = (const float*)d_in[13];
    float* out = (float*)d_out;
    float* ws  = (float*)d_ws;

    // ---- workspace layout ----
    // floats: x [0,3.2M) (later aliased by hb0), h1 [3.2M,9.6M), sb0 [9.6M,12.8M)
    float* x   = ws;
    float* h1  = ws + 3200000;
    float* sb0 = ws + 9600000;
    float* hb0 = ws;                 // alias x: x dead after G3, hb0 written after
    // ints/u16 from float offset 12.8M (51.2 MB)
    int* ib       = (int*)(ws + 12800000);
    int* deg_g    = ib;              // 50000
    int* deg_f    = ib + 50000;      // 50000   (contiguous with deg_g for memset)
    int* rp_g     = ib + 100000;     // 50001
    int* rp_f     = ib + 150001;     // 50001
    int* cur_g    = ib + 200002;     // 50000
    int* cur_f    = ib + 250002;     // 50000
    u16* adj_g    = (u16*)(ib + 300002);   // 800000 u16
    u16* adj_f    = (u16*)(ib + 700002);   // 800000 u16
    // total ws use ~55.6 MB

    const int eblocks = (N_EDGES + 255) / 256;   // 3125
    const int gblocks = (N_NODES + 63) / 64;     // 782

    // CSR build (int atomics only; all tables L2-resident)
    hipMemsetAsync(deg_g, 0, 2 * N_NODES * sizeof(int), stream);
    hist_k<<<eblocks, 256, 0, stream>>>(dst_g, deg_g, N_EDGES);
    hist_k<<<eblocks, 256, 0, stream>>>(dst_f, deg_f, N_EDGES);
    scan_k<<<1, 1024, 0, stream>>>(deg_g, rp_g, cur_g, N_NODES);
    scan_k<<<1, 1024, 0, stream>>>(deg_f, rp_f, cur_f, N_NODES);
    scatter_k<<<eblocks, 256, 0, stream>>>(src_g, dst_g, cur_g, adj_g, N_EDGES);
    scatter_k<<<eblocks, 256, 0, stream>>>(src_f, dst_f, cur_f, adj_f, N_EDGES);

    // x = features * mask
    int n4 = N_NODES * IN_F / 4;
    mul_mask_k<<<(n4 + 255) / 256, 256, 0, stream>>>(features, mask, x, n4);

    // h1 = (x @ W1) * ng ; sb0 = (x @ ws) * nf
    gemm_k<64, 128><<<gblocks, 256, 0, stream>>>(x, W1, norm_g, h1, N_NODES);
    gemm_k<64, 64><<<gblocks, 256, 0, stream>>>(x, wsw, norm_f, sb0, N_NODES);

    // hb0 = ng * (relu(aggG(h1)*ng + b1) @ wh)
    agg_matvec_k<<<1024, 256, 0, stream>>>(h1, rp_g, adj_g, norm_g, b1, wh, hb0);

    // out = sigmoid(aggG(hb0)*ng + bh + aggF(sb0)*nf + bs)
    final_agg_k<<<(N_NODES + 3) / 4, 256, 0, stream>>>(hb0, sb0, rp_g, adj_g,
                                                       rp_f, adj_f, norm_g, norm_f,
                                                       bh, bs, out);
}

// Round 5
// 557.100 us; speedup vs baseline: 5.1635x; 1.2674x over previous
//
#include <hip/hip_runtime.h>

#define N_NODES 50000
#define N_EDGES 800000
#define IN_F 64
#define H_F 128

typedef unsigned short u16;

static __device__ __forceinline__ float4 ld4(const float* p) {
    return *reinterpret_cast<const float4*>(p);
}
static __device__ __forceinline__ void st4(float* p, float4 v) {
    *reinterpret_cast<float4*>(p) = v;
}

// -------------------- y = features * mask * ng[n] --------------------
__global__ __launch_bounds__(256) void mulmask_scale_k(const float* __restrict__ f,
        const float* __restrict__ m, const float* __restrict__ ng,
        float* __restrict__ y) {
    int i = blockIdx.x * 256 + threadIdx.x;           // float4 chunk id
    if (i >= N_NODES * (IN_F / 4)) return;
    int n = i >> 4;
    float s = ng[n];
    float4 a = ld4(f + 4 * i);
    float4 b = ld4(m + 4 * i);
    float4 r;
    r.x = a.x * b.x * s; r.y = a.y * b.y * s;
    r.z = a.z * b.z * s; r.w = a.w * b.w * s;
    st4(y + 4 * i, r);
}

// -------------------- CSR build --------------------
__global__ __launch_bounds__(256) void hist2_k(const int* __restrict__ dg,
        const int* __restrict__ df, int* __restrict__ deg_g,
        int* __restrict__ deg_f) {
    int i = blockIdx.x * 256 + threadIdx.x;
    if (i < N_EDGES) atomicAdd(&deg_g[dg[i]], 1);
    else {
        int j = i - N_EDGES;
        if (j < N_EDGES) atomicAdd(&deg_f[df[j]], 1);
    }
}

// 2 blocks: block 0 scans graph g, block 1 graph f
__global__ __launch_bounds__(1024) void scan2_k(
        const int* __restrict__ deg_g, int* __restrict__ rp_g, int* __restrict__ cur_g,
        const int* __restrict__ deg_f, int* __restrict__ rp_f, int* __restrict__ cur_f) {
    const int* deg = blockIdx.x ? deg_f : deg_g;
    int* rowptr    = blockIdx.x ? rp_f : rp_g;
    int* cur       = blockIdx.x ? cur_f : cur_g;
    const int n = N_NODES;
    __shared__ int part[1024];
    const int tid = threadIdx.x;
    const int chunk = (n + 1023) / 1024;
    const int lo = tid * chunk;
    const int hi = min(lo + chunk, n);
    int s = 0;
    for (int i = lo; i < hi; ++i) s += deg[i];
    part[tid] = s;
    __syncthreads();
    for (int off = 1; off < 1024; off <<= 1) {
        int v = (tid >= off) ? part[tid - off] : 0;
        __syncthreads();
        part[tid] += v;
        __syncthreads();
    }
    int ex = (tid == 0) ? 0 : part[tid - 1];
    for (int i = lo; i < hi; ++i) {
        rowptr[i] = ex;
        cur[i] = ex;
        ex += deg[i];
    }
    if (tid == 1023) rowptr[n] = ex;
}

__global__ __launch_bounds__(256) void scatter2_k(
        const int* __restrict__ sg, const int* __restrict__ dg, int* __restrict__ cur_g,
        u16* __restrict__ adj_g,
        const int* __restrict__ sf, const int* __restrict__ df, int* __restrict__ cur_f,
        u16* __restrict__ adj_f) {
    int i = blockIdx.x * 256 + threadIdx.x;
    if (i < N_EDGES) {
        int p = atomicAdd(&cur_g[dg[i]], 1);
        adj_g[p] = (u16)sg[i];
    } else {
        int j = i - N_EDGES;
        if (j < N_EDGES) {
            int p = atomicAdd(&cur_f[df[j]], 1);
            adj_f[p] = (u16)sf[j];
        }
    }
}

// -------------------- CSR segment-sum, 64-feat rows: out[n] = sum_src tbl[src]
__global__ __launch_bounds__(256) void agg64_k(const float* __restrict__ tbl,
        const int* __restrict__ rp, const u16* __restrict__ adj,
        float* __restrict__ out) {
    const int wv = threadIdx.x >> 6, lane = threadIdx.x & 63;
    const int n = blockIdx.x * 4 + wv;
    if (n >= N_NODES) return;
    int e = rp[n];
    const int e1 = rp[n + 1];
    float acc = 0.f;
    for (; e + 8 <= e1; e += 8) {
        int s0 = adj[e], s1 = adj[e + 1], s2 = adj[e + 2], s3 = adj[e + 3];
        int s4 = adj[e + 4], s5 = adj[e + 5], s6 = adj[e + 6], s7 = adj[e + 7];
        float a0 = tbl[(s0 << 6) + lane];
        float a1 = tbl[(s1 << 6) + lane];
        float a2 = tbl[(s2 << 6) + lane];
        float a3 = tbl[(s3 << 6) + lane];
        float a4 = tbl[(s4 << 6) + lane];
        float a5 = tbl[(s5 << 6) + lane];
        float a6 = tbl[(s6 << 6) + lane];
        float a7 = tbl[(s7 << 6) + lane];
        acc += ((a0 + a1) + (a2 + a3)) + ((a4 + a5) + (a6 + a7));
    }
    for (; e < e1; ++e) acc += tbl[(adj[e] << 6) + lane];
    out[(n << 6) + lane] = acc;
}

// -------------------- tiled fp32 GEMM --------------------
// out[n][c] = EPI( sum_k A'[n][k] * W[k][c] )
// SMODE 0: A' = A          SMODE 1: A' = A * A2 (elementwise mask)
// EPI 0: o = acc           EPI 1: o = relu(acc*rs[n] + bias[c])   EPI 2: o = acc*rs[n]
template<int K, int N, int SMODE, int EPI>
__global__ __launch_bounds__(256) void gemm_k(
    const float* __restrict__ A, const float* __restrict__ A2,
    const float* __restrict__ W, const float* __restrict__ rs,
    const float* __restrict__ bias, float* __restrict__ out, int M)
{
    constexpr int CPT = N / 16;
    constexpr int AS  = K + 1;
    constexpr int KQ  = K / 4;
    __shared__ __align__(16) float Wl[K * N];
    __shared__ __align__(16) float Al[64 * AS];

    const int tid = threadIdx.x;
    const int n0  = blockIdx.x << 6;

    for (int i = tid; i < K * N / 4; i += 256) st4(&Wl[4 * i], ld4(W + 4 * i));
    for (int i4 = tid; i4 < 64 * KQ; i4 += 256) {
        int n  = i4 / KQ;
        int k4 = (i4 & (KQ - 1)) << 2;
        int gn = n0 + n;
        float4 v = make_float4(0.f, 0.f, 0.f, 0.f);
        if (gn < M) {
            v = ld4(A + gn * K + k4);
            if (SMODE == 1) {
                float4 m4 = ld4(A2 + gn * K + k4);
                v.x *= m4.x; v.y *= m4.y; v.z *= m4.z; v.w *= m4.w;
            }
        }
        float* p = &Al[n * AS + k4];
        p[0] = v.x; p[1] = v.y; p[2] = v.z; p[3] = v.w;
    }
    __syncthreads();

    const int tr = tid & 15;
    const int tc = tid >> 4;

    float acc[4][CPT];
#pragma unroll
    for (int i = 0; i < 4; ++i)
#pragma unroll
        for (int j = 0; j < CPT; ++j) acc[i][j] = 0.f;

#pragma unroll 4
    for (int k = 0; k < K; ++k) {
        float a0 = Al[(4 * tr + 0) * AS + k];
        float a1 = Al[(4 * tr + 1) * AS + k];
        float a2 = Al[(4 * tr + 2) * AS + k];
        float a3 = Al[(4 * tr + 3) * AS + k];
#pragma unroll
        for (int jq = 0; jq < CPT / 4; ++jq) {
            float4 w = ld4(&Wl[k * N + tc * CPT + 4 * jq]);
            acc[0][4 * jq + 0] += a0 * w.x; acc[0][4 * jq + 1] += a0 * w.y;
            acc[0][4 * jq + 2] += a0 * w.z; acc[0][4 * jq + 3] += a0 * w.w;
            acc[1][4 * jq + 0] += a1 * w.x; acc[1][4 * jq + 1] += a1 * w.y;
            acc[1][4 * jq + 2] += a1 * w.z; acc[1][4 * jq + 3] += a1 * w.w;
            acc[2][4 * jq + 0] += a2 * w.x; acc[2][4 * jq + 1] += a2 * w.y;
            acc[2][4 * jq + 2] += a2 * w.z; acc[2][4 * jq + 3] += a2 * w.w;
            acc[3][4 * jq + 0] += a3 * w.x; acc[3][4 * jq + 1] += a3 * w.y;
            acc[3][4 * jq + 2] += a3 * w.z; acc[3][4 * jq + 3] += a3 * w.w;
        }
    }

#pragma unroll
    for (int i = 0; i < 4; ++i) {
        int gn = n0 + 4 * tr + i;
        if (gn >= M) continue;
        float s = (EPI != 0) ? rs[gn] : 1.f;
#pragma unroll
        for (int jq = 0; jq < CPT / 4; ++jq) {
            float4 o;
            if (EPI == 1) {
                float4 b4 = ld4(bias + tc * CPT + 4 * jq);
                o.x = fmaxf(fmaf(acc[i][4 * jq + 0], s, b4.x), 0.f);
                o.y = fmaxf(fmaf(acc[i][4 * jq + 1], s, b4.y), 0.f);
                o.z = fmaxf(fmaf(acc[i][4 * jq + 2], s, b4.z), 0.f);
                o.w = fmaxf(fmaf(acc[i][4 * jq + 3], s, b4.w), 0.f);
            } else if (EPI == 2) {
                o.x = acc[i][4 * jq + 0] * s; o.y = acc[i][4 * jq + 1] * s;
                o.z = acc[i][4 * jq + 2] * s; o.w = acc[i][4 * jq + 3] * s;
            } else {
                o.x = acc[i][4 * jq + 0]; o.y = acc[i][4 * jq + 1];
                o.z = acc[i][4 * jq + 2]; o.w = acc[i][4 * jq + 3];
            }
            st4(out + gn * N + tc * CPT + 4 * jq, o);
        }
    }
}

// -------------------- fused final: two 64-wide CSR aggs + bias + sigmoid ----
__global__ __launch_bounds__(256) void final2_k(
    const float* __restrict__ hb, const float* __restrict__ sb,
    const int* __restrict__ rp_g, const u16* __restrict__ adj_g,
    const int* __restrict__ rp_f, const u16* __restrict__ adj_f,
    const float* __restrict__ ng, const float* __restrict__ nf,
    const float* __restrict__ bh, const float* __restrict__ bs,
    float* __restrict__ out)
{
    const int wv = threadIdx.x >> 6, lane = threadIdx.x & 63;
    const int n = blockIdx.x * 4 + wv;
    if (n >= N_NODES) return;

    float accg = 0.f;
    {
        int e = rp_g[n];
        const int e1 = rp_g[n + 1];
        for (; e + 8 <= e1; e += 8) {
            int s0 = adj_g[e], s1 = adj_g[e + 1], s2 = adj_g[e + 2], s3 = adj_g[e + 3];
            int s4 = adj_g[e + 4], s5 = adj_g[e + 5], s6 = adj_g[e + 6], s7 = adj_g[e + 7];
            float a0 = hb[(s0 << 6) + lane];
            float a1 = hb[(s1 << 6) + lane];
            float a2 = hb[(s2 << 6) + lane];
            float a3 = hb[(s3 << 6) + lane];
            float a4 = hb[(s4 << 6) + lane];
            float a5 = hb[(s5 << 6) + lane];
            float a6 = hb[(s6 << 6) + lane];
            float a7 = hb[(s7 << 6) + lane];
            accg += ((a0 + a1) + (a2 + a3)) + ((a4 + a5) + (a6 + a7));
        }
        for (; e < e1; ++e) accg += hb[(adj_g[e] << 6) + lane];
    }
    float accf = 0.f;
    {
        int e = rp_f[n];
        const int e1 = rp_f[n + 1];
        for (; e + 8 <= e1; e += 8) {
            int s0 = adj_f[e], s1 = adj_f[e + 1], s2 = adj_f[e + 2], s3 = adj_f[e + 3];
            int s4 = adj_f[e + 4], s5 = adj_f[e + 5], s6 = adj_f[e + 6], s7 = adj_f[e + 7];
            float a0 = sb[(s0 << 6) + lane];
            float a1 = sb[(s1 << 6) + lane];
            float a2 = sb[(s2 << 6) + lane];
            float a3 = sb[(s3 << 6) + lane];
            float a4 = sb[(s4 << 6) + lane];
            float a5 = sb[(s5 << 6) + lane];
            float a6 = sb[(s6 << 6) + lane];
            float a7 = sb[(s7 << 6) + lane];
            accf += ((a0 + a1) + (a2 + a3)) + ((a4 + a5) + (a6 + a7));
        }
        for (; e < e1; ++e) accf += sb[(adj_f[e] << 6) + lane];
    }
    float t = accg * ng[n] + bh[lane] + accf * nf[n] + bs[lane];
    out[(n << 6) + lane] = 1.f / (1.f + expf(-t));
}

extern "C" void kernel_launch(void* const* d_in, const int* in_sizes, int n_in,
                              void* d_out, int out_size, void* d_ws, size_t ws_size,
                              hipStream_t stream) {
    const float* features = (const float*)d_in[0];
    const float* mask     = (const float*)d_in[1];
    const float* norm_g   = (const float*)d_in[2];
    const float* norm_f   = (const float*)d_in[3];
    const int*   src_g    = (const int*)d_in[4];
    const int*   dst_g    = (const int*)d_in[5];
    const int*   src_f    = (const int*)d_in[6];
    const int*   dst_f    = (const int*)d_in[7];
    const float* W1  = (const float*)d_in[8];
    const float* b1  = (const float*)d_in[9];
    const float* wh  = (const float*)d_in[10];
    const float* bh  = (const float*)d_in[11];
    const float* wsw = (const float*)d_in[12];
    const float* bs  = (const float*)d_in[13];
    float* out = (float*)d_out;
    float* ws  = (float*)d_ws;

    // ---- workspace (floats) ----
    float* y   = ws;                 // [0, 3.2M)   y = features*mask*ng ; dead after agg64
    float* z   = ws + 3200000;       // [3.2M,6.4M) z = aggG(y) ; dead after gemm1
    float* t1  = ws + 6400000;       // [6.4M,12.8M) t1 = relu((z@W1)*ng+b1)
    float* hb0 = ws;                 // alias y
    float* sb0 = ws + 3200000;       // alias z
    // ints/u16 from float offset 12.8M
    int* ib    = (int*)(ws + 12800000);
    int* deg_g = ib;                 // 50000
    int* deg_f = ib + 50000;         // 50000  (contiguous for one memset)
    int* rp_g  = ib + 100000;        // 50001
    int* rp_f  = ib + 150001;        // 50001
    int* cur_g = ib + 200002;        // 50000
    int* cur_f = ib + 250002;        // 50000
    u16* adj_g = (u16*)(ib + 300002);   // 800000 u16
    u16* adj_f = (u16*)(ib + 700002);   // 800000 u16

    const int e2blocks = (2 * N_EDGES + 255) / 256;  // 6250
    const int gblocks  = (N_NODES + 63) / 64;        // 782
    const int nblocks  = (N_NODES + 3) / 4;          // 12500

    // CSR build (both graphs per kernel)
    hipMemsetAsync(deg_g, 0, 2 * N_NODES * sizeof(int), stream);
    hist2_k<<<e2blocks, 256, 0, stream>>>(dst_g, dst_f, deg_g, deg_f);
    scan2_k<<<2, 1024, 0, stream>>>(deg_g, rp_g, cur_g, deg_f, rp_f, cur_f);
    scatter2_k<<<e2blocks, 256, 0, stream>>>(src_g, dst_g, cur_g, adj_g,
                                             src_f, dst_f, cur_f, adj_f);

    // y = features*mask*ng
    mulmask_scale_k<<<(N_NODES * 16 + 255) / 256, 256, 0, stream>>>(features, mask,
                                                                    norm_g, y);
    // z = aggG(y)      [ == agg before the 64->128 expansion; linearity of segsum ]
    agg64_k<<<nblocks, 256, 0, stream>>>(y, rp_g, adj_g, z);

    // t1 = relu((z@W1)*ng + b1)
    gemm_k<64, 128, 0, 1><<<gblocks, 256, 0, stream>>>(z, nullptr, W1, norm_g, b1,
                                                       t1, N_NODES);
    // hb0 = (t1@wh)*ng
    gemm_k<128, 64, 0, 2><<<gblocks, 256, 0, stream>>>(t1, nullptr, wh, norm_g,
                                                       nullptr, hb0, N_NODES);
    // sb0 = ((features*mask)@ws)*nf
    gemm_k<64, 64, 1, 2><<<gblocks, 256, 0, stream>>>(features, mask, wsw, norm_f,
                                                      nullptr, sb0, N_NODES);

    // out = sigmoid(aggG(hb0)*ng + bh + aggF(sb0)*nf + bs)
    final2_k<<<nblocks, 256, 0, stream>>>(hb0, sb0, rp_g, adj_g, rp_f, adj_f,
                                          norm_g, norm_f, bh, bs, out);
}

// Round 6
// 330.138 us; speedup vs baseline: 8.7133x; 1.6875x over previous
//
#include <hip/hip_runtime.h>

#define N_NODES 50000
#define N_EDGES 800000
#define IN_F 64
#define H_F 128
#define NBUK 49          // node buckets of 1024: bucket = dst >> 10
#define EPB 2048         // edges per block in P1/P2
#define NBLK 391         // ceil(N_EDGES / EPB)

typedef unsigned short u16;
typedef unsigned int u32;

static __device__ __forceinline__ float4 ld4(const float* p) {
    return *reinterpret_cast<const float4*>(p);
}
static __device__ __forceinline__ void st4(float* p, float4 v) {
    *reinterpret_cast<float4*>(p) = v;
}

// ---------- P1: per-(block,bucket) edge counts for both graphs + fused y = f*m*ng
__global__ __launch_bounds__(256) void p1_count_k(
    const int* __restrict__ dst_g, const int* __restrict__ dst_f,
    int* __restrict__ cnt_g, int* __restrict__ cnt_f,
    const float* __restrict__ f, const float* __restrict__ m,
    const float* __restrict__ ng, float* __restrict__ y)
{
    __shared__ int c[NBUK];
    const int tid = threadIdx.x;
    const int graph = blockIdx.x >= NBLK;
    const int blk = blockIdx.x - graph * NBLK;
    const int* dst = graph ? dst_f : dst_g;
    int* cnt = graph ? cnt_f : cnt_g;
    if (tid < NBUK) c[tid] = 0;
    __syncthreads();
    const int e0 = blk * EPB;
    const int e1 = min(e0 + EPB, N_EDGES);
    for (int e = e0 + tid; e < e1; e += 256) atomicAdd(&c[dst[e] >> 10], 1);
    __syncthreads();
    if (tid < NBUK) cnt[tid * NBLK + blk] = c[tid];
    // fused: y = features * mask * ng (grid-stride over float4 chunks)
    for (int i = blockIdx.x * 256 + tid; i < N_NODES * (IN_F / 4);
         i += gridDim.x * 256) {
        int n = i >> 4;
        float s = ng[n];
        float4 a = ld4(f + 4 * i);
        float4 b = ld4(m + 4 * i);
        float4 r;
        r.x = a.x * b.x * s; r.y = a.y * b.y * s;
        r.z = a.z * b.z * s; r.w = a.w * b.w * s;
        st4(y + 4 * i, r);
    }
}

// ---------- S1: exclusive scan of cnt[NBUK][NBLK] -> off, plus bucket bases bb
__global__ __launch_bounds__(1024) void s1_scan_k(
    const int* __restrict__ cnt_g, int* __restrict__ off_g, int* __restrict__ bb_g,
    const int* __restrict__ cnt_f, int* __restrict__ off_f, int* __restrict__ bb_f)
{
    __shared__ int part[1024];
    const int tid = threadIdx.x;
    const int TOT = NBUK * NBLK;                 // 19159
    const int chunk = (TOT + 1023) / 1024;       // 19
    for (int g = 0; g < 2; ++g) {
        const int* cnt = g ? cnt_f : cnt_g;
        int* off = g ? off_f : off_g;
        int* bb  = g ? bb_f  : bb_g;
        const int lo = tid * chunk;
        const int hi = min(lo + chunk, TOT);
        int s = 0;
        for (int i = lo; i < hi; ++i) s += cnt[i];
        part[tid] = s;
        __syncthreads();
        for (int o = 1; o < 1024; o <<= 1) {
            int v = (tid >= o) ? part[tid - o] : 0;
            __syncthreads();
            part[tid] += v;
            __syncthreads();
        }
        int ex = (tid == 0) ? 0 : part[tid - 1];
        for (int i = lo; i < hi; ++i) {
            off[i] = ex;
            if (i % NBLK == 0) bb[i / NBLK] = ex;
            ex += cnt[i];
        }
        if (tid == 0) bb[NBUK] = N_EDGES;
        __syncthreads();                          // before part reuse next graph
    }
}

// ---------- P2: partition edges into bucket-contiguous packed records
__global__ __launch_bounds__(256) void p2_part_k(
    const int* __restrict__ src_g, const int* __restrict__ dst_g,
    const int* __restrict__ off_g, u32* __restrict__ rec_g,
    const int* __restrict__ src_f, const int* __restrict__ dst_f,
    const int* __restrict__ off_f, u32* __restrict__ rec_f)
{
    __shared__ int base[NBUK];
    __shared__ int cur[NBUK];
    const int tid = threadIdx.x;
    const int graph = blockIdx.x >= NBLK;
    const int blk = blockIdx.x - graph * NBLK;
    const int* src = graph ? src_f : src_g;
    const int* dst = graph ? dst_f : dst_g;
    const int* off = graph ? off_f : off_g;
    u32* rec = graph ? rec_f : rec_g;
    if (tid < NBUK) { base[tid] = off[tid * NBLK + blk]; cur[tid] = 0; }
    __syncthreads();
    const int e0 = blk * EPB;
    const int e1 = min(e0 + EPB, N_EDGES);
    for (int e = e0 + tid; e < e1; e += 256) {
        int d = dst[e], s = src[e];
        int b = d >> 10;
        int p = atomicAdd(&cur[b], 1);
        rec[base[b] + p] = ((u32)s << 16) | (u32)d;
    }
}

// ---------- P3: per-bucket LDS hist + scan -> rowptr; LDS-cursor scatter -> adj
__global__ __launch_bounds__(1024) void p3_build_k(
    const u32* __restrict__ rec_g, const int* __restrict__ bb_g,
    int* __restrict__ rp_g, u16* __restrict__ adj_g,
    const u32* __restrict__ rec_f, const int* __restrict__ bb_f,
    int* __restrict__ rp_f, u16* __restrict__ adj_f)
{
    __shared__ int hist[1024];
    __shared__ int tmp[1024];
    const int tid = threadIdx.x;
    const int graph = blockIdx.x >= NBUK;
    const int b = blockIdx.x - graph * NBUK;
    const u32* rec = graph ? rec_f : rec_g;
    const int* bb  = graph ? bb_f  : bb_g;
    int* rp  = graph ? rp_f : rp_g;
    u16* adj = graph ? adj_f : adj_g;
    const int e_base = bb[b];
    const int e_cnt  = bb[b + 1] - e_base;
    hist[tid] = 0;
    __syncthreads();
    for (int i = tid; i < e_cnt; i += 1024)
        atomicAdd(&hist[rec[e_base + i] & 1023], 1);
    __syncthreads();
    const int v = hist[tid];
    tmp[tid] = v;
    __syncthreads();
    for (int o = 1; o < 1024; o <<= 1) {
        int t = (tid >= o) ? tmp[tid - o] : 0;
        __syncthreads();
        tmp[tid] += t;
        __syncthreads();
    }
    const int excl = tmp[tid] - v;                // exclusive within bucket
    const int n = (b << 10) + tid;
    if (n < N_NODES) rp[n] = e_base + excl;
    if (b == NBUK - 1 && tid == 0) rp[N_NODES] = N_EDGES;
    hist[tid] = excl;                             // becomes cursor
    __syncthreads();
    for (int i = tid; i < e_cnt; i += 1024) {
        u32 r = rec[e_base + i];
        int p = atomicAdd(&hist[r & 1023], 1);
        adj[e_base + p] = (u16)(r >> 16);         // single CU -> L2-local writes
    }
}

// ---------- CSR row gather-sum helper (64-wide rows), unroll 16 ----------
static __device__ __forceinline__ float csr_row_sum(const float* __restrict__ tbl,
        const u16* __restrict__ adj, int e, int e1, int lane) {
    float acc = 0.f;
    for (; e + 16 <= e1; e += 16) {
        int s_[16];
        float a_[16];
#pragma unroll
        for (int j = 0; j < 16; ++j) s_[j] = adj[e + j];
#pragma unroll
        for (int j = 0; j < 16; ++j) a_[j] = tbl[(s_[j] << 6) + lane];
        float t0 = ((a_[0] + a_[1]) + (a_[2] + a_[3])) +
                   ((a_[4] + a_[5]) + (a_[6] + a_[7]));
        float t1 = ((a_[8] + a_[9]) + (a_[10] + a_[11])) +
                   ((a_[12] + a_[13]) + (a_[14] + a_[15]));
        acc += t0 + t1;
    }
    for (; e + 4 <= e1; e += 4) {
        int s0 = adj[e], s1 = adj[e + 1], s2 = adj[e + 2], s3 = adj[e + 3];
        float a0 = tbl[(s0 << 6) + lane];
        float a1 = tbl[(s1 << 6) + lane];
        float a2 = tbl[(s2 << 6) + lane];
        float a3 = tbl[(s3 << 6) + lane];
        acc += (a0 + a1) + (a2 + a3);
    }
    for (; e < e1; ++e) acc += tbl[(adj[e] << 6) + lane];
    return acc;
}

// ---------- agg64: out[n] = sum_{src in N(n)} tbl[src]  (64-wide) ----------
__global__ __launch_bounds__(256) void agg64_k(const float* __restrict__ tbl,
        const int* __restrict__ rp, const u16* __restrict__ adj,
        float* __restrict__ out) {
    const int wv = threadIdx.x >> 6, lane = threadIdx.x & 63;
    const int n = blockIdx.x * 4 + wv;
    if (n >= N_NODES) return;
    float acc = csr_row_sum(tbl, adj, rp[n], rp[n + 1], lane);
    out[(n << 6) + lane] = acc;
}

// ---------- tiled fp32 GEMM (as round 2/5, correctness-proven) ----------
// out[n][c] = EPI( sum_k A'[n][k] * W[k][c] )
// SMODE 0: A' = A   SMODE 1: A' = A * A2
// EPI 1: relu(acc*rs[n] + bias[c])   EPI 2: acc*rs[n]
template<int K, int N, int SMODE, int EPI>
__global__ __launch_bounds__(256) void gemm_k(
    const float* __restrict__ A, const float* __restrict__ A2,
    const float* __restrict__ W, const float* __restrict__ rs,
    const float* __restrict__ bias, float* __restrict__ out, int M)
{
    constexpr int CPT = N / 16;
    constexpr int AS  = K + 1;
    constexpr int KQ  = K / 4;
    __shared__ __align__(16) float Wl[K * N];
    __shared__ __align__(16) float Al[64 * AS];

    const int tid = threadIdx.x;
    const int n0  = blockIdx.x << 6;

    for (int i = tid; i < K * N / 4; i += 256) st4(&Wl[4 * i], ld4(W + 4 * i));
    for (int i4 = tid; i4 < 64 * KQ; i4 += 256) {
        int n  = i4 / KQ;
        int k4 = (i4 & (KQ - 1)) << 2;
        int gn = n0 + n;
        float4 v = make_float4(0.f, 0.f, 0.f, 0.f);
        if (gn < M) {
            v = ld4(A + gn * K + k4);
            if (SMODE == 1) {
                float4 m4 = ld4(A2 + gn * K + k4);
                v.x *= m4.x; v.y *= m4.y; v.z *= m4.z; v.w *= m4.w;
            }
        }
        float* p = &Al[n * AS + k4];
        p[0] = v.x; p[1] = v.y; p[2] = v.z; p[3] = v.w;
    }
    __syncthreads();

    const int tr = tid & 15;
    const int tc = tid >> 4;

    float acc[4][CPT];
#pragma unroll
    for (int i = 0; i < 4; ++i)
#pragma unroll
        for (int j = 0; j < CPT; ++j) acc[i][j] = 0.f;

#pragma unroll 4
    for (int k = 0; k < K; ++k) {
        float a0 = Al[(4 * tr + 0) * AS + k];
        float a1 = Al[(4 * tr + 1) * AS + k];
        float a2 = Al[(4 * tr + 2) * AS + k];
        float a3 = Al[(4 * tr + 3) * AS + k];
#pragma unroll
        for (int jq = 0; jq < CPT / 4; ++jq) {
            float4 w = ld4(&Wl[k * N + tc * CPT + 4 * jq]);
            acc[0][4 * jq + 0] += a0 * w.x; acc[0][4 * jq + 1] += a0 * w.y;
            acc[0][4 * jq + 2] += a0 * w.z; acc[0][4 * jq + 3] += a0 * w.w;
            acc[1][4 * jq + 0] += a1 * w.x; acc[1][4 * jq + 1] += a1 * w.y;
            acc[1][4 * jq + 2] += a1 * w.z; acc[1][4 * jq + 3] += a1 * w.w;
            acc[2][4 * jq + 0] += a2 * w.x; acc[2][4 * jq + 1] += a2 * w.y;
            acc[2][4 * jq + 2] += a2 * w.z; acc[2][4 * jq + 3] += a2 * w.w;
            acc[3][4 * jq + 0] += a3 * w.x; acc[3][4 * jq + 1] += a3 * w.y;
            acc[3][4 * jq + 2] += a3 * w.z; acc[3][4 * jq + 3] += a3 * w.w;
        }
    }

#pragma unroll
    for (int i = 0; i < 4; ++i) {
        int gn = n0 + 4 * tr + i;
        if (gn >= M) continue;
        float s = (EPI != 0) ? rs[gn] : 1.f;
#pragma unroll
        for (int jq = 0; jq < CPT / 4; ++jq) {
            float4 o;
            if (EPI == 1) {
                float4 b4 = ld4(bias + tc * CPT + 4 * jq);
                o.x = fmaxf(fmaf(acc[i][4 * jq + 0], s, b4.x), 0.f);
                o.y = fmaxf(fmaf(acc[i][4 * jq + 1], s, b4.y), 0.f);
                o.z = fmaxf(fmaf(acc[i][4 * jq + 2], s, b4.z), 0.f);
                o.w = fmaxf(fmaf(acc[i][4 * jq + 3], s, b4.w), 0.f);
            } else {
                o.x = acc[i][4 * jq + 0] * s; o.y = acc[i][4 * jq + 1] * s;
                o.z = acc[i][4 * jq + 2] * s; o.w = acc[i][4 * jq + 3] * s;
            }
            st4(out + gn * N + tc * CPT + 4 * jq, o);
        }
    }
}

// ---------- fused final: two 64-wide CSR aggs + bias + sigmoid ----------
__global__ __launch_bounds__(256) void final2_k(
    const float* __restrict__ hb, const float* __restrict__ sb,
    const int* __restrict__ rp_g, const u16* __restrict__ adj_g,
    const int* __restrict__ rp_f, const u16* __restrict__ adj_f,
    const float* __restrict__ ng, const float* __restrict__ nf,
    const float* __restrict__ bh, const float* __restrict__ bs,
    float* __restrict__ out)
{
    const int wv = threadIdx.x >> 6, lane = threadIdx.x & 63;
    const int n = blockIdx.x * 4 + wv;
    if (n >= N_NODES) return;
    float accg = csr_row_sum(hb, adj_g, rp_g[n], rp_g[n + 1], lane);
    float accf = csr_row_sum(sb, adj_f, rp_f[n], rp_f[n + 1], lane);
    float t = accg * ng[n] + bh[lane] + accf * nf[n] + bs[lane];
    out[(n << 6) + lane] = 1.f / (1.f + expf(-t));
}

extern "C" void kernel_launch(void* const* d_in, const int* in_sizes, int n_in,
                              void* d_out, int out_size, void* d_ws, size_t ws_size,
                              hipStream_t stream) {
    const float* features = (const float*)d_in[0];
    const float* mask     = (const float*)d_in[1];
    const float* norm_g   = (const float*)d_in[2];
    const float* norm_f   = (const float*)d_in[3];
    const int*   src_g    = (const int*)d_in[4];
    const int*   dst_g    = (const int*)d_in[5];
    const int*   src_f    = (const int*)d_in[6];
    const int*   dst_f    = (const int*)d_in[7];
    const float* W1  = (const float*)d_in[8];
    const float* b1  = (const float*)d_in[9];
    const float* wh  = (const float*)d_in[10];
    const float* bh  = (const float*)d_in[11];
    const float* wsw = (const float*)d_in[12];
    const float* bs  = (const float*)d_in[13];
    float* out = (float*)d_out;
    float* ws  = (float*)d_ws;

    // ---- workspace layout (lifetime-aliased) ----
    // floats:
    //   [0      , 3.2M)  y   (dead after agg64)  -> hb0 (gemm2 output)
    //   [3.2M   , 6.4M)  z   (dead after gemm1)  -> sb0 (gemm3 output)
    //   [6.4M   ,12.8M)  rec/cnt/off scratch (dead after P3) -> t1 (gemm1 out)
    // persistent ints at [12.8M floats):
    //   rp_g[50001] rp_f[50001] bb_g[50] bb_f[50] adj_g[800k u16] adj_f[800k u16]
    float* y   = ws;
    float* z   = ws + 3200000;
    float* t1  = ws + 6400000;
    float* hb0 = ws;              // alias y
    float* sb0 = ws + 3200000;    // alias z
    int* creg  = (int*)(ws + 6400000);     // build scratch (aliases t1)
    u32* rec_g = (u32*)creg;               // 800000
    u32* rec_f = (u32*)(creg + 800000);    // 800000
    int* cnt_g = creg + 1600000;           // 19159
    int* cnt_f = creg + 1619159;           // 19159
    int* off_g = creg + 1638318;           // 19159
    int* off_f = creg + 1657477;           // 19159 (end 1676636 < 6.4M)
    int* pers  = (int*)(ws + 12800000);
    int* rp_g  = pers;                     // 50001
    int* rp_f  = pers + 50001;             // 50001
    int* bb_g  = pers + 100002;            // 50
    int* bb_f  = pers + 100052;            // 50
    u16* adj_g = (u16*)(pers + 100102);    // 800000 u16
    u16* adj_f = (u16*)(pers + 500102);    // 800000 u16
    // total ws use ~54.8 MB

    const int gblocks = (N_NODES + 63) / 64;   // 782
    const int nblocks = (N_NODES + 3) / 4;     // 12500

    // CSR build, zero HBM atomics (LDS-only), both graphs per kernel
    p1_count_k<<<2 * NBLK, 256, 0, stream>>>(dst_g, dst_f, cnt_g, cnt_f,
                                             features, mask, norm_g, y);
    s1_scan_k<<<1, 1024, 0, stream>>>(cnt_g, off_g, bb_g, cnt_f, off_f, bb_f);
    p2_part_k<<<2 * NBLK, 256, 0, stream>>>(src_g, dst_g, off_g, rec_g,
                                            src_f, dst_f, off_f, rec_f);
    p3_build_k<<<2 * NBUK, 1024, 0, stream>>>(rec_g, bb_g, rp_g, adj_g,
                                              rec_f, bb_f, rp_f, adj_f);

    // z = aggG(y)   [agg before the 64->128 expansion; linearity of segsum]
    agg64_k<<<nblocks, 256, 0, stream>>>(y, rp_g, adj_g, z);

    // t1 = relu((z@W1)*ng + b1)      (t1 overwrites dead rec/cnt scratch)
    gemm_k<64, 128, 0, 1><<<gblocks, 256, 0, stream>>>(z, nullptr, W1, norm_g, b1,
                                                       t1, N_NODES);
    // hb0 = (t1@wh)*ng
    gemm_k<128, 64, 0, 2><<<gblocks, 256, 0, stream>>>(t1, nullptr, wh, norm_g,
                                                       nullptr, hb0, N_NODES);
    // sb0 = ((features*mask)@ws)*nf
    gemm_k<64, 64, 1, 2><<<gblocks, 256, 0, stream>>>(features, mask, wsw, norm_f,
                                                      nullptr, sb0, N_NODES);

    // out = sigmoid(aggG(hb0)*ng + bh + aggF(sb0)*nf + bs)
    final2_k<<<nblocks, 256, 0, stream>>>(hb0, sb0, rp_g, adj_g, rp_f, adj_f,
                                          norm_g, norm_f, bh, bs, out);
}

// Round 7
// 321.522 us; speedup vs baseline: 8.9468x; 1.0268x over previous
//
#include <hip/hip_runtime.h>
#include <hip/hip_fp16.h>

#define N_NODES 50000
#define N_EDGES 800000
#define IN_F 64
#define H_F 128
#define NBUK 49          // node buckets of 1024: bucket = dst >> 10
#define EPB 2048         // edges per block in P1/P2
#define NBLK 391         // ceil(N_EDGES / EPB)

typedef unsigned short u16;
typedef unsigned int u32;

static __device__ __forceinline__ float4 ld4(const float* p) {
    return *reinterpret_cast<const float4*>(p);
}
static __device__ __forceinline__ void st4(float* p, float4 v) {
    *reinterpret_cast<float4*>(p) = v;
}
// pack float4 -> 4 fp16 (8 B store)
static __device__ __forceinline__ void st_h4(__half* p, float4 v) {
    union { __half h[4]; uint2 u; } pk;
    pk.h[0] = __float2half_rn(v.x);
    pk.h[1] = __float2half_rn(v.y);
    pk.h[2] = __float2half_rn(v.z);
    pk.h[3] = __float2half_rn(v.w);
    *reinterpret_cast<uint2*>(p) = pk.u;
}

// ---------- P1: per-(block,bucket) edge counts for both graphs + fused y = f*m*ng (fp16)
__global__ __launch_bounds__(256) void p1_count_k(
    const int* __restrict__ dst_g, const int* __restrict__ dst_f,
    int* __restrict__ cnt_g, int* __restrict__ cnt_f,
    const float* __restrict__ f, const float* __restrict__ m,
    const float* __restrict__ ng, __half* __restrict__ y)
{
    __shared__ int c[NBUK];
    const int tid = threadIdx.x;
    const int graph = blockIdx.x >= NBLK;
    const int blk = blockIdx.x - graph * NBLK;
    const int* dst = graph ? dst_f : dst_g;
    int* cnt = graph ? cnt_f : cnt_g;
    if (tid < NBUK) c[tid] = 0;
    __syncthreads();
    const int e0 = blk * EPB;
    const int e1 = min(e0 + EPB, N_EDGES);
    for (int e = e0 + tid; e < e1; e += 256) atomicAdd(&c[dst[e] >> 10], 1);
    __syncthreads();
    if (tid < NBUK) cnt[tid * NBLK + blk] = c[tid];
    // fused: y = features * mask * ng, stored fp16
    for (int i = blockIdx.x * 256 + tid; i < N_NODES * (IN_F / 4);
         i += gridDim.x * 256) {
        int n = i >> 4;
        float s = ng[n];
        float4 a = ld4(f + 4 * i);
        float4 b = ld4(m + 4 * i);
        float4 r;
        r.x = a.x * b.x * s; r.y = a.y * b.y * s;
        r.z = a.z * b.z * s; r.w = a.w * b.w * s;
        st_h4(y + 4 * i, r);
    }
}

// ---------- S1: exclusive scan of cnt[NBUK][NBLK] -> off, plus bucket bases bb
__global__ __launch_bounds__(1024) void s1_scan_k(
    const int* __restrict__ cnt_g, int* __restrict__ off_g, int* __restrict__ bb_g,
    const int* __restrict__ cnt_f, int* __restrict__ off_f, int* __restrict__ bb_f)
{
    __shared__ int part[1024];
    const int tid = threadIdx.x;
    const int TOT = NBUK * NBLK;                 // 19159
    const int chunk = (TOT + 1023) / 1024;       // 19
    for (int g = 0; g < 2; ++g) {
        const int* cnt = g ? cnt_f : cnt_g;
        int* off = g ? off_f : off_g;
        int* bb  = g ? bb_f  : bb_g;
        const int lo = tid * chunk;
        const int hi = min(lo + chunk, TOT);
        int s = 0;
        for (int i = lo; i < hi; ++i) s += cnt[i];
        part[tid] = s;
        __syncthreads();
        for (int o = 1; o < 1024; o <<= 1) {
            int v = (tid >= o) ? part[tid - o] : 0;
            __syncthreads();
            part[tid] += v;
            __syncthreads();
        }
        int ex = (tid == 0) ? 0 : part[tid - 1];
        for (int i = lo; i < hi; ++i) {
            off[i] = ex;
            if (i % NBLK == 0) bb[i / NBLK] = ex;
            ex += cnt[i];
        }
        if (tid == 0) bb[NBUK] = N_EDGES;
        __syncthreads();                          // before part reuse next graph
    }
}

// ---------- P2: partition edges into bucket-contiguous packed records
__global__ __launch_bounds__(256) void p2_part_k(
    const int* __restrict__ src_g, const int* __restrict__ dst_g,
    const int* __restrict__ off_g, u32* __restrict__ rec_g,
    const int* __restrict__ src_f, const int* __restrict__ dst_f,
    const int* __restrict__ off_f, u32* __restrict__ rec_f)
{
    __shared__ int base[NBUK];
    __shared__ int cur[NBUK];
    const int tid = threadIdx.x;
    const int graph = blockIdx.x >= NBLK;
    const int blk = blockIdx.x - graph * NBLK;
    const int* src = graph ? src_f : src_g;
    const int* dst = graph ? dst_f : dst_g;
    const int* off = graph ? off_f : off_g;
    u32* rec = graph ? rec_f : rec_g;
    if (tid < NBUK) { base[tid] = off[tid * NBLK + blk]; cur[tid] = 0; }
    __syncthreads();
    const int e0 = blk * EPB;
    const int e1 = min(e0 + EPB, N_EDGES);
    for (int e = e0 + tid; e < e1; e += 256) {
        int d = dst[e], s = src[e];
        int b = d >> 10;
        int p = atomicAdd(&cur[b], 1);
        rec[base[b] + p] = ((u32)s << 16) | (u32)d;
    }
}

// ---------- P3: per-bucket LDS hist + scan -> rowptr; LDS-cursor scatter -> adj
__global__ __launch_bounds__(1024) void p3_build_k(
    const u32* __restrict__ rec_g, const int* __restrict__ bb_g,
    int* __restrict__ rp_g, u16* __restrict__ adj_g,
    const u32* __restrict__ rec_f, const int* __restrict__ bb_f,
    int* __restrict__ rp_f, u16* __restrict__ adj_f)
{
    __shared__ int hist[1024];
    __shared__ int tmp[1024];
    const int tid = threadIdx.x;
    const int graph = blockIdx.x >= NBUK;
    const int b = blockIdx.x - graph * NBUK;
    const u32* rec = graph ? rec_f : rec_g;
    const int* bb  = graph ? bb_f  : bb_g;
    int* rp  = graph ? rp_f : rp_g;
    u16* adj = graph ? adj_f : adj_g;
    const int e_base = bb[b];
    const int e_cnt  = bb[b + 1] - e_base;
    hist[tid] = 0;
    __syncthreads();
    for (int i = tid; i < e_cnt; i += 1024)
        atomicAdd(&hist[rec[e_base + i] & 1023], 1);
    __syncthreads();
    const int v = hist[tid];
    tmp[tid] = v;
    __syncthreads();
    for (int o = 1; o < 1024; o <<= 1) {
        int t = (tid >= o) ? tmp[tid - o] : 0;
        __syncthreads();
        tmp[tid] += t;
        __syncthreads();
    }
    const int excl = tmp[tid] - v;                // exclusive within bucket
    const int n = (b << 10) + tid;
    if (n < N_NODES) rp[n] = e_base + excl;
    if (b == NBUK - 1 && tid == 0) rp[N_NODES] = N_EDGES;
    hist[tid] = excl;                             // becomes cursor
    __syncthreads();
    for (int i = tid; i < e_cnt; i += 1024) {
        u32 r = rec[e_base + i];
        int p = atomicAdd(&hist[r & 1023], 1);
        adj[e_base + p] = (u16)(r >> 16);         // single CU -> L2-local writes
    }
}

// ---------- CSR row gather-sum, fp16 table (128 B/row), fp32 accumulate ----------
static __device__ __forceinline__ float csr_row_sum_h(const __half* __restrict__ tbl,
        const u16* __restrict__ adj, int e, int e1, int lane) {
    float acc = 0.f;
    for (; e + 16 <= e1; e += 16) {
        int s_[16];
        float a_[16];
#pragma unroll
        for (int j = 0; j < 16; ++j) s_[j] = adj[e + j];
#pragma unroll
        for (int j = 0; j < 16; ++j) a_[j] = __half2float(tbl[(s_[j] << 6) + lane]);
        float t0 = ((a_[0] + a_[1]) + (a_[2] + a_[3])) +
                   ((a_[4] + a_[5]) + (a_[6] + a_[7]));
        float t1 = ((a_[8] + a_[9]) + (a_[10] + a_[11])) +
                   ((a_[12] + a_[13]) + (a_[14] + a_[15]));
        acc += t0 + t1;
    }
    for (; e + 4 <= e1; e += 4) {
        int s0 = adj[e], s1 = adj[e + 1], s2 = adj[e + 2], s3 = adj[e + 3];
        float a0 = __half2float(tbl[(s0 << 6) + lane]);
        float a1 = __half2float(tbl[(s1 << 6) + lane]);
        float a2 = __half2float(tbl[(s2 << 6) + lane]);
        float a3 = __half2float(tbl[(s3 << 6) + lane]);
        acc += (a0 + a1) + (a2 + a3);
    }
    for (; e < e1; ++e) acc += __half2float(tbl[(adj[e] << 6) + lane]);
    return acc;
}

// ---------- agg64: z[n] (fp32) = sum_{src in N(n)} y16[src] ----------
__global__ __launch_bounds__(256) void agg64_k(const __half* __restrict__ tbl,
        const int* __restrict__ rp, const u16* __restrict__ adj,
        float* __restrict__ out) {
    const int wv = threadIdx.x >> 6, lane = threadIdx.x & 63;
    const int n = blockIdx.x * 4 + wv;
    if (n >= N_NODES) return;
    float acc = csr_row_sum_h(tbl, adj, rp[n], rp[n + 1], lane);
    out[(n << 6) + lane] = acc;
}

// ---------- tiled fp32 GEMM ----------
// out[n][c] = EPI( sum_k A'[n][k] * W[k][c] )
// SMODE 0: A' = A   SMODE 1: A' = A * A2
// EPI 1: relu(acc*rs[n] + bias[c]) -> fp32 out   EPI 2: acc*rs[n] -> out (fp16 if OUT16)
template<int K, int N, int SMODE, int EPI, int OUT16>
__global__ __launch_bounds__(256) void gemm_k(
    const float* __restrict__ A, const float* __restrict__ A2,
    const float* __restrict__ W, const float* __restrict__ rs,
    const float* __restrict__ bias, void* __restrict__ outv, int M)
{
    constexpr int CPT = N / 16;
    constexpr int AS  = K + 1;
    constexpr int KQ  = K / 4;
    __shared__ __align__(16) float Wl[K * N];
    __shared__ __align__(16) float Al[64 * AS];

    const int tid = threadIdx.x;
    const int n0  = blockIdx.x << 6;

    for (int i = tid; i < K * N / 4; i += 256) st4(&Wl[4 * i], ld4(W + 4 * i));
    for (int i4 = tid; i4 < 64 * KQ; i4 += 256) {
        int n  = i4 / KQ;
        int k4 = (i4 & (KQ - 1)) << 2;
        int gn = n0 + n;
        float4 v = make_float4(0.f, 0.f, 0.f, 0.f);
        if (gn < M) {
            v = ld4(A + gn * K + k4);
            if (SMODE == 1) {
                float4 m4 = ld4(A2 + gn * K + k4);
                v.x *= m4.x; v.y *= m4.y; v.z *= m4.z; v.w *= m4.w;
            }
        }
        float* p = &Al[n * AS + k4];
        p[0] = v.x; p[1] = v.y; p[2] = v.z; p[3] = v.w;
    }
    __syncthreads();

    const int tr = tid & 15;
    const int tc = tid >> 4;

    float acc[4][CPT];
#pragma unroll
    for (int i = 0; i < 4; ++i)
#pragma unroll
        for (int j = 0; j < CPT; ++j) acc[i][j] = 0.f;

#pragma unroll 4
    for (int k = 0; k < K; ++k) {
        float a0 = Al[(4 * tr + 0) * AS + k];
        float a1 = Al[(4 * tr + 1) * AS + k];
        float a2 = Al[(4 * tr + 2) * AS + k];
        float a3 = Al[(4 * tr + 3) * AS + k];
#pragma unroll
        for (int jq = 0; jq < CPT / 4; ++jq) {
            float4 w = ld4(&Wl[k * N + tc * CPT + 4 * jq]);
            acc[0][4 * jq + 0] += a0 * w.x; acc[0][4 * jq + 1] += a0 * w.y;
            acc[0][4 * jq + 2] += a0 * w.z; acc[0][4 * jq + 3] += a0 * w.w;
            acc[1][4 * jq + 0] += a1 * w.x; acc[1][4 * jq + 1] += a1 * w.y;
            acc[1][4 * jq + 2] += a1 * w.z; acc[1][4 * jq + 3] += a1 * w.w;
            acc[2][4 * jq + 0] += a2 * w.x; acc[2][4 * jq + 1] += a2 * w.y;
            acc[2][4 * jq + 2] += a2 * w.z; acc[2][4 * jq + 3] += a2 * w.w;
            acc[3][4 * jq + 0] += a3 * w.x; acc[3][4 * jq + 1] += a3 * w.y;
            acc[3][4 * jq + 2] += a3 * w.z; acc[3][4 * jq + 3] += a3 * w.w;
        }
    }

#pragma unroll
    for (int i = 0; i < 4; ++i) {
        int gn = n0 + 4 * tr + i;
        if (gn >= M) continue;
        float s = rs[gn];
#pragma unroll
        for (int jq = 0; jq < CPT / 4; ++jq) {
            float4 o;
            if (EPI == 1) {
                float4 b4 = ld4(bias + tc * CPT + 4 * jq);
                o.x = fmaxf(fmaf(acc[i][4 * jq + 0], s, b4.x), 0.f);
                o.y = fmaxf(fmaf(acc[i][4 * jq + 1], s, b4.y), 0.f);
                o.z = fmaxf(fmaf(acc[i][4 * jq + 2], s, b4.z), 0.f);
                o.w = fmaxf(fmaf(acc[i][4 * jq + 3], s, b4.w), 0.f);
            } else {
                o.x = acc[i][4 * jq + 0] * s; o.y = acc[i][4 * jq + 1] * s;
                o.z = acc[i][4 * jq + 2] * s; o.w = acc[i][4 * jq + 3] * s;
            }
            if (OUT16) {
                st_h4((__half*)outv + gn * N + tc * CPT + 4 * jq, o);
            } else {
                st4((float*)outv + gn * N + tc * CPT + 4 * jq, o);
            }
        }
    }
}

// ---------- fused final: two 64-wide fp16 CSR aggs + bias + sigmoid ----------
__global__ __launch_bounds__(256) void final2_k(
    const __half* __restrict__ hb, const __half* __restrict__ sb,
    const int* __restrict__ rp_g, const u16* __restrict__ adj_g,
    const int* __restrict__ rp_f, const u16* __restrict__ adj_f,
    const float* __restrict__ ng, const float* __restrict__ nf,
    const float* __restrict__ bh, const float* __restrict__ bs,
    float* __restrict__ out)
{
    const int wv = threadIdx.x >> 6, lane = threadIdx.x & 63;
    const int n = blockIdx.x * 4 + wv;
    if (n >= N_NODES) return;
    float accg = csr_row_sum_h(hb, adj_g, rp_g[n], rp_g[n + 1], lane);
    float accf = csr_row_sum_h(sb, adj_f, rp_f[n], rp_f[n + 1], lane);
    float t = accg * ng[n] + bh[lane] + accf * nf[n] + bs[lane];
    out[(n << 6) + lane] = 1.f / (1.f + expf(-t));
}

extern "C" void kernel_launch(void* const* d_in, const int* in_sizes, int n_in,
                              void* d_out, int out_size, void* d_ws, size_t ws_size,
                              hipStream_t stream) {
    const float* features = (const float*)d_in[0];
    const float* mask     = (const float*)d_in[1];
    const float* norm_g   = (const float*)d_in[2];
    const float* norm_f   = (const float*)d_in[3];
    const int*   src_g    = (const int*)d_in[4];
    const int*   dst_g    = (const int*)d_in[5];
    const int*   src_f    = (const int*)d_in[6];
    const int*   dst_f    = (const int*)d_in[7];
    const float* W1  = (const float*)d_in[8];
    const float* b1  = (const float*)d_in[9];
    const float* wh  = (const float*)d_in[10];
    const float* bh  = (const float*)d_in[11];
    const float* wsw = (const float*)d_in[12];
    const float* bs  = (const float*)d_in[13];
    float* out = (float*)d_out;
    float* ws  = (float*)d_ws;

    // ---- workspace layout (float-unit offsets, lifetime-aliased) ----
    //   [0      , 3.2M)  y (fp16, 6.4MB)   dead after agg64 -> hb0 (fp16, gemm2 out)
    //   [3.2M   , 6.4M)  z (fp32)          dead after gemm1 -> sb0 (fp16, gemm3 out)
    //   [6.4M   ,12.8M)  rec/cnt/off build scratch, dead after P3 -> t1 (fp32)
    // persistent ints at [12.8M):
    //   rp_g[50001] rp_f[50001] bb_g[50] bb_f[50] adj_g[800k u16] adj_f[800k u16]
    __half* y   = (__half*)ws;
    float*  z   = ws + 3200000;
    float*  t1  = ws + 6400000;
    __half* hb0 = (__half*)ws;              // alias y
    __half* sb0 = (__half*)(ws + 3200000);  // alias z
    int* creg  = (int*)(ws + 6400000);      // build scratch (aliases t1)
    u32* rec_g = (u32*)creg;                // 800000
    u32* rec_f = (u32*)(creg + 800000);     // 800000
    int* cnt_g = creg + 1600000;            // 19159
    int* cnt_f = creg + 1619159;            // 19159
    int* off_g = creg + 1638318;            // 19159
    int* off_f = creg + 1657477;            // 19159 (end 1676636 < 6.4M)
    int* pers  = (int*)(ws + 12800000);
    int* rp_g  = pers;                      // 50001
    int* rp_f  = pers + 50001;              // 50001
    int* bb_g  = pers + 100002;             // 50
    int* bb_f  = pers + 100052;             // 50
    u16* adj_g = (u16*)(pers + 100102);     // 800000 u16
    u16* adj_f = (u16*)(pers + 500102);     // 800000 u16

    const int gblocks = (N_NODES + 63) / 64;   // 782
    const int nblocks = (N_NODES + 3) / 4;     // 12500

    // CSR build, zero HBM atomics (LDS-only), both graphs per kernel
    p1_count_k<<<2 * NBLK, 256, 0, stream>>>(dst_g, dst_f, cnt_g, cnt_f,
                                             features, mask, norm_g, y);
    s1_scan_k<<<1, 1024, 0, stream>>>(cnt_g, off_g, bb_g, cnt_f, off_f, bb_f);
    p2_part_k<<<2 * NBLK, 256, 0, stream>>>(src_g, dst_g, off_g, rec_g,
                                            src_f, dst_f, off_f, rec_f);
    p3_build_k<<<2 * NBUK, 1024, 0, stream>>>(rec_g, bb_g, rp_g, adj_g,
                                              rec_f, bb_f, rp_f, adj_f);

    // z = aggG(y)   [agg before the 64->128 expansion; linearity of segsum]
    agg64_k<<<nblocks, 256, 0, stream>>>(y, rp_g, adj_g, z);

    // t1 = relu((z@W1)*ng + b1)   (fp32; overwrites dead build scratch)
    gemm_k<64, 128, 0, 1, 0><<<gblocks, 256, 0, stream>>>(z, nullptr, W1, norm_g,
                                                          b1, (void*)t1, N_NODES);
    // hb0 = (t1@wh)*ng   (fp16 out)
    gemm_k<128, 64, 0, 2, 1><<<gblocks, 256, 0, stream>>>(t1, nullptr, wh, norm_g,
                                                          nullptr, (void*)hb0, N_NODES);
    // sb0 = ((features*mask)@ws)*nf   (fp16 out)
    gemm_k<64, 64, 1, 2, 1><<<gblocks, 256, 0, stream>>>(features, mask, wsw, norm_f,
                                                         nullptr, (void*)sb0, N_NODES);

    // out = sigmoid(aggG(hb0)*ng + bh + aggF(sb0)*nf + bs)
    final2_k<<<nblocks, 256, 0, stream>>>(hb0, sb0, rp_g, adj_g, rp_f, adj_f,
                                          norm_g, norm_f, bh, bs, out);
}

// Round 8
// 294.182 us; speedup vs baseline: 9.7783x; 1.0929x over previous
//
#include <hip/hip_runtime.h>
#include <hip/hip_fp16.h>

#define N_NODES 50000
#define N_EDGES 800000
#define IN_F 64
#define H_F 128
#define NBUK 49          // node buckets of 1024: bucket = dst >> 10
#define EPB 2048         // edges per block in P1/P2
#define NBLK 391         // ceil(N_EDGES / EPB)

typedef unsigned short u16;
typedef unsigned int u32;

static __device__ __forceinline__ float4 ld4(const float* p) {
    return *reinterpret_cast<const float4*>(p);
}
static __device__ __forceinline__ void st4(float* p, float4 v) {
    *reinterpret_cast<float4*>(p) = v;
}
// pack float4 -> 4 fp16 (8 B store)
static __device__ __forceinline__ void st_h4(__half* p, float4 v) {
    union { __half h[4]; uint2 u; } pk;
    pk.h[0] = __float2half_rn(v.x);
    pk.h[1] = __float2half_rn(v.y);
    pk.h[2] = __float2half_rn(v.z);
    pk.h[3] = __float2half_rn(v.w);
    *reinterpret_cast<uint2*>(p) = pk.u;
}
// acc += 4 halfs packed in uint2
static __device__ __forceinline__ void add_h4(float4& a, uint2 r) {
    __half2* p = reinterpret_cast<__half2*>(&r);
    float2 f0 = __half22float2(p[0]);
    float2 f1 = __half22float2(p[1]);
    a.x += f0.x; a.y += f0.y; a.z += f1.x; a.w += f1.y;
}

// ---------- P1: per-(block,bucket) edge counts for both graphs + fused y = f*m*ng (fp16)
__global__ __launch_bounds__(256) void p1_count_k(
    const int* __restrict__ dst_g, const int* __restrict__ dst_f,
    int* __restrict__ cnt_g, int* __restrict__ cnt_f,
    const float* __restrict__ f, const float* __restrict__ m,
    const float* __restrict__ ng, __half* __restrict__ y)
{
    __shared__ int c[NBUK];
    const int tid = threadIdx.x;
    const int graph = blockIdx.x >= NBLK;
    const int blk = blockIdx.x - graph * NBLK;
    const int* dst = graph ? dst_f : dst_g;
    int* cnt = graph ? cnt_f : cnt_g;
    if (tid < NBUK) c[tid] = 0;
    __syncthreads();
    const int e0 = blk * EPB;
    const int e1 = min(e0 + EPB, N_EDGES);
    for (int e = e0 + tid; e < e1; e += 256) atomicAdd(&c[dst[e] >> 10], 1);
    __syncthreads();
    if (tid < NBUK) cnt[tid * NBLK + blk] = c[tid];
    // fused: y = features * mask * ng, stored fp16
    for (int i = blockIdx.x * 256 + tid; i < N_NODES * (IN_F / 4);
         i += gridDim.x * 256) {
        int n = i >> 4;
        float s = ng[n];
        float4 a = ld4(f + 4 * i);
        float4 b = ld4(m + 4 * i);
        float4 r;
        r.x = a.x * b.x * s; r.y = a.y * b.y * s;
        r.z = a.z * b.z * s; r.w = a.w * b.w * s;
        st_h4(y + 4 * i, r);
    }
}

// ---------- S1: exclusive scan of cnt[NBUK][NBLK] -> off, plus bucket bases bb
__global__ __launch_bounds__(1024) void s1_scan_k(
    const int* __restrict__ cnt_g, int* __restrict__ off_g, int* __restrict__ bb_g,
    const int* __restrict__ cnt_f, int* __restrict__ off_f, int* __restrict__ bb_f)
{
    __shared__ int part[1024];
    const int tid = threadIdx.x;
    const int TOT = NBUK * NBLK;                 // 19159
    const int chunk = (TOT + 1023) / 1024;       // 19
    for (int g = 0; g < 2; ++g) {
        const int* cnt = g ? cnt_f : cnt_g;
        int* off = g ? off_f : off_g;
        int* bb  = g ? bb_f  : bb_g;
        const int lo = tid * chunk;
        const int hi = min(lo + chunk, TOT);
        int s = 0;
        for (int i = lo; i < hi; ++i) s += cnt[i];
        part[tid] = s;
        __syncthreads();
        for (int o = 1; o < 1024; o <<= 1) {
            int v = (tid >= o) ? part[tid - o] : 0;
            __syncthreads();
            part[tid] += v;
            __syncthreads();
        }
        int ex = (tid == 0) ? 0 : part[tid - 1];
        for (int i = lo; i < hi; ++i) {
            off[i] = ex;
            if (i % NBLK == 0) bb[i / NBLK] = ex;
            ex += cnt[i];
        }
        if (tid == 0) bb[NBUK] = N_EDGES;
        __syncthreads();                          // before part reuse next graph
    }
}

// ---------- P2: partition edges into bucket-contiguous packed records
__global__ __launch_bounds__(256) void p2_part_k(
    const int* __restrict__ src_g, const int* __restrict__ dst_g,
    const int* __restrict__ off_g, u32* __restrict__ rec_g,
    const int* __restrict__ src_f, const int* __restrict__ dst_f,
    const int* __restrict__ off_f, u32* __restrict__ rec_f)
{
    __shared__ int base[NBUK];
    __shared__ int cur[NBUK];
    const int tid = threadIdx.x;
    const int graph = blockIdx.x >= NBLK;
    const int blk = blockIdx.x - graph * NBLK;
    const int* src = graph ? src_f : src_g;
    const int* dst = graph ? dst_f : dst_g;
    const int* off = graph ? off_f : off_g;
    u32* rec = graph ? rec_f : rec_g;
    if (tid < NBUK) { base[tid] = off[tid * NBLK + blk]; cur[tid] = 0; }
    __syncthreads();
    const int e0 = blk * EPB;
    const int e1 = min(e0 + EPB, N_EDGES);
    for (int e = e0 + tid; e < e1; e += 256) {
        int d = dst[e], s = src[e];
        int b = d >> 10;
        int p = atomicAdd(&cur[b], 1);
        rec[base[b] + p] = ((u32)s << 16) | (u32)d;
    }
}

// ---------- P3: per-bucket LDS hist + scan -> rowptr; LDS-cursor scatter -> adj
__global__ __launch_bounds__(1024) void p3_build_k(
    const u32* __restrict__ rec_g, const int* __restrict__ bb_g,
    int* __restrict__ rp_g, u16* __restrict__ adj_g,
    const u32* __restrict__ rec_f, const int* __restrict__ bb_f,
    int* __restrict__ rp_f, u16* __restrict__ adj_f)
{
    __shared__ int hist[1024];
    __shared__ int tmp[1024];
    const int tid = threadIdx.x;
    const int graph = blockIdx.x >= NBUK;
    const int b = blockIdx.x - graph * NBUK;
    const u32* rec = graph ? rec_f : rec_g;
    const int* bb  = graph ? bb_f  : bb_g;
    int* rp  = graph ? rp_f : rp_g;
    u16* adj = graph ? adj_f : adj_g;
    const int e_base = bb[b];
    const int e_cnt  = bb[b + 1] - e_base;
    hist[tid] = 0;
    __syncthreads();
    for (int i = tid; i < e_cnt; i += 1024)
        atomicAdd(&hist[rec[e_base + i] & 1023], 1);
    __syncthreads();
    const int v = hist[tid];
    tmp[tid] = v;
    __syncthreads();
    for (int o = 1; o < 1024; o <<= 1) {
        int t = (tid >= o) ? tmp[tid - o] : 0;
        __syncthreads();
        tmp[tid] += t;
        __syncthreads();
    }
    const int excl = tmp[tid] - v;                // exclusive within bucket
    const int n = (b << 10) + tid;
    if (n < N_NODES) rp[n] = e_base + excl;
    if (b == NBUK - 1 && tid == 0) rp[N_NODES] = N_EDGES;
    hist[tid] = excl;                             // becomes cursor
    __syncthreads();
    for (int i = tid; i < e_cnt; i += 1024) {
        u32 r = rec[e_base + i];
        int p = atomicAdd(&hist[r & 1023], 1);
        adj[e_base + p] = (u16)(r >> 16);         // single CU -> L2-local writes
    }
}

// ---------- CSR row gather-sum, 16-lane group, half4 (8 B) per lane ----------
// Lane `fl` (0..15) accumulates features [4*fl .. 4*fl+3] of its group's node.
// One gather VMEM instruction per wave covers 4 edges (4 groups x 128 B rows).
static __device__ __forceinline__ float4 csr_row_sum_h4(
        const __half* __restrict__ tbl, const u16* __restrict__ adj,
        int e, int e1, int off) {
    float4 acc = make_float4(0.f, 0.f, 0.f, 0.f);
    for (; e + 4 <= e1; e += 4) {
        int s0 = adj[e], s1 = adj[e + 1], s2 = adj[e + 2], s3 = adj[e + 3];
        uint2 r0 = *reinterpret_cast<const uint2*>(tbl + (s0 << 6) + off);
        uint2 r1 = *reinterpret_cast<const uint2*>(tbl + (s1 << 6) + off);
        uint2 r2 = *reinterpret_cast<const uint2*>(tbl + (s2 << 6) + off);
        uint2 r3 = *reinterpret_cast<const uint2*>(tbl + (s3 << 6) + off);
        add_h4(acc, r0); add_h4(acc, r1); add_h4(acc, r2); add_h4(acc, r3);
    }
    for (; e < e1; ++e) {
        uint2 r = *reinterpret_cast<const uint2*>(tbl + (adj[e] << 6) + off);
        add_h4(acc, r);
    }
    return acc;
}

// ---------- agg64: z[n] (fp32) = sum_{src in N(n)} y16[src]; 16 nodes/block ----------
__global__ __launch_bounds__(256) void agg64_k(const __half* __restrict__ tbl,
        const int* __restrict__ rp, const u16* __restrict__ adj,
        float* __restrict__ out) {
    const int tid = threadIdx.x;
    const int fl = tid & 15;                  // feature part (4 feats)
    const int n  = blockIdx.x * 16 + (tid >> 4);
    if (n >= N_NODES) return;
    float4 acc = csr_row_sum_h4(tbl, adj, rp[n], rp[n + 1], fl << 2);
    st4(out + (n << 6) + (fl << 2), acc);
}

// ---------- tiled fp32 GEMM ----------
// out[n][c] = EPI( sum_k A'[n][k] * W[k][c] )
// SMODE 0: A' = A   SMODE 1: A' = A * A2
// EPI 1: relu(acc*rs[n] + bias[c]) -> fp32 out   EPI 2: acc*rs[n] -> out (fp16 if OUT16)
template<int K, int N, int SMODE, int EPI, int OUT16>
__global__ __launch_bounds__(256) void gemm_k(
    const float* __restrict__ A, const float* __restrict__ A2,
    const float* __restrict__ W, const float* __restrict__ rs,
    const float* __restrict__ bias, void* __restrict__ outv, int M)
{
    constexpr int CPT = N / 16;
    constexpr int AS  = K + 1;
    constexpr int KQ  = K / 4;
    __shared__ __align__(16) float Wl[K * N];
    __shared__ __align__(16) float Al[64 * AS];

    const int tid = threadIdx.x;
    const int n0  = blockIdx.x << 6;

    for (int i = tid; i < K * N / 4; i += 256) st4(&Wl[4 * i], ld4(W + 4 * i));
    for (int i4 = tid; i4 < 64 * KQ; i4 += 256) {
        int n  = i4 / KQ;
        int k4 = (i4 & (KQ - 1)) << 2;
        int gn = n0 + n;
        float4 v = make_float4(0.f, 0.f, 0.f, 0.f);
        if (gn < M) {
            v = ld4(A + gn * K + k4);
            if (SMODE == 1) {
                float4 m4 = ld4(A2 + gn * K + k4);
                v.x *= m4.x; v.y *= m4.y; v.z *= m4.z; v.w *= m4.w;
            }
        }
        float* p = &Al[n * AS + k4];
        p[0] = v.x; p[1] = v.y; p[2] = v.z; p[3] = v.w;
    }
    __syncthreads();

    const int tr = tid & 15;
    const int tc = tid >> 4;

    float acc[4][CPT];
#pragma unroll
    for (int i = 0; i < 4; ++i)
#pragma unroll
        for (int j = 0; j < CPT; ++j) acc[i][j] = 0.f;

#pragma unroll 4
    for (int k = 0; k < K; ++k) {
        float a0 = Al[(4 * tr + 0) * AS + k];
        float a1 = Al[(4 * tr + 1) * AS + k];
        float a2 = Al[(4 * tr + 2) * AS + k];
        float a3 = Al[(4 * tr + 3) * AS + k];
#pragma unroll
        for (int jq = 0; jq < CPT / 4; ++jq) {
            float4 w = ld4(&Wl[k * N + tc * CPT + 4 * jq]);
            acc[0][4 * jq + 0] += a0 * w.x; acc[0][4 * jq + 1] += a0 * w.y;
            acc[0][4 * jq + 2] += a0 * w.z; acc[0][4 * jq + 3] += a0 * w.w;
            acc[1][4 * jq + 0] += a1 * w.x; acc[1][4 * jq + 1] += a1 * w.y;
            acc[1][4 * jq + 2] += a1 * w.z; acc[1][4 * jq + 3] += a1 * w.w;
            acc[2][4 * jq + 0] += a2 * w.x; acc[2][4 * jq + 1] += a2 * w.y;
            acc[2][4 * jq + 2] += a2 * w.z; acc[2][4 * jq + 3] += a2 * w.w;
            acc[3][4 * jq + 0] += a3 * w.x; acc[3][4 * jq + 1] += a3 * w.y;
            acc[3][4 * jq + 2] += a3 * w.z; acc[3][4 * jq + 3] += a3 * w.w;
        }
    }

#pragma unroll
    for (int i = 0; i < 4; ++i) {
        int gn = n0 + 4 * tr + i;
        if (gn >= M) continue;
        float s = rs[gn];
#pragma unroll
        for (int jq = 0; jq < CPT / 4; ++jq) {
            float4 o;
            if (EPI == 1) {
                float4 b4 = ld4(bias + tc * CPT + 4 * jq);
                o.x = fmaxf(fmaf(acc[i][4 * jq + 0], s, b4.x), 0.f);
                o.y = fmaxf(fmaf(acc[i][4 * jq + 1], s, b4.y), 0.f);
                o.z = fmaxf(fmaf(acc[i][4 * jq + 2], s, b4.z), 0.f);
                o.w = fmaxf(fmaf(acc[i][4 * jq + 3], s, b4.w), 0.f);
            } else {
                o.x = acc[i][4 * jq + 0] * s; o.y = acc[i][4 * jq + 1] * s;
                o.z = acc[i][4 * jq + 2] * s; o.w = acc[i][4 * jq + 3] * s;
            }
            if (OUT16) {
                st_h4((__half*)outv + gn * N + tc * CPT + 4 * jq, o);
            } else {
                st4((float*)outv + gn * N + tc * CPT + 4 * jq, o);
            }
        }
    }
}

// ---------- fused final: two fp16 CSR aggs + bias + sigmoid; 16 nodes/block ----------
__global__ __launch_bounds__(256) void final2_k(
    const __half* __restrict__ hb, const __half* __restrict__ sb,
    const int* __restrict__ rp_g, const u16* __restrict__ adj_g,
    const int* __restrict__ rp_f, const u16* __restrict__ adj_f,
    const float* __restrict__ ng, const float* __restrict__ nf,
    const float* __restrict__ bh, const float* __restrict__ bs,
    float* __restrict__ out)
{
    const int tid = threadIdx.x;
    const int fl = tid & 15;
    const int n  = blockIdx.x * 16 + (tid >> 4);
    if (n >= N_NODES) return;
    const int off = fl << 2;
    float4 accg = csr_row_sum_h4(hb, adj_g, rp_g[n], rp_g[n + 1], off);
    float4 accf = csr_row_sum_h4(sb, adj_f, rp_f[n], rp_f[n + 1], off);
    const float g = ng[n], f = nf[n];
    float4 b4 = ld4(bh + off);
    float4 s4 = ld4(bs + off);
    float4 o;
    float t;
    t = accg.x * g + b4.x + accf.x * f + s4.x; o.x = 1.f / (1.f + expf(-t));
    t = accg.y * g + b4.y + accf.y * f + s4.y; o.y = 1.f / (1.f + expf(-t));
    t = accg.z * g + b4.z + accf.z * f + s4.z; o.z = 1.f / (1.f + expf(-t));
    t = accg.w * g + b4.w + accf.w * f + s4.w; o.w = 1.f / (1.f + expf(-t));
    st4(out + (n << 6) + off, o);
}

extern "C" void kernel_launch(void* const* d_in, const int* in_sizes, int n_in,
                              void* d_out, int out_size, void* d_ws, size_t ws_size,
                              hipStream_t stream) {
    const float* features = (const float*)d_in[0];
    const float* mask     = (const float*)d_in[1];
    const float* norm_g   = (const float*)d_in[2];
    const float* norm_f   = (const float*)d_in[3];
    const int*   src_g    = (const int*)d_in[4];
    const int*   dst_g    = (const int*)d_in[5];
    const int*   src_f    = (const int*)d_in[6];
    const int*   dst_f    = (const int*)d_in[7];
    const float* W1  = (const float*)d_in[8];
    const float* b1  = (const float*)d_in[9];
    const float* wh  = (const float*)d_in[10];
    const float* bh  = (const float*)d_in[11];
    const float* wsw = (const float*)d_in[12];
    const float* bs  = (const float*)d_in[13];
    float* out = (float*)d_out;
    float* ws  = (float*)d_ws;

    // ---- workspace layout (float-unit offsets, lifetime-aliased) ----
    //   [0      , 3.2M)  y (fp16, 6.4MB)   dead after agg64 -> hb0 (fp16, gemm2 out)
    //   [3.2M   , 6.4M)  z (fp32)          dead after gemm1 -> sb0 (fp16, gemm3 out)
    //   [6.4M   ,12.8M)  rec/cnt/off build scratch, dead after P3 -> t1 (fp32)
    // persistent ints at [12.8M):
    //   rp_g[50001] rp_f[50001] bb_g[50] bb_f[50] adj_g[800k u16] adj_f[800k u16]
    __half* y   = (__half*)ws;
    float*  z   = ws + 3200000;
    float*  t1  = ws + 6400000;
    __half* hb0 = (__half*)ws;              // alias y
    __half* sb0 = (__half*)(ws + 3200000);  // alias z
    int* creg  = (int*)(ws + 6400000);      // build scratch (aliases t1)
    u32* rec_g = (u32*)creg;                // 800000
    u32* rec_f = (u32*)(creg + 800000);     // 800000
    int* cnt_g = creg + 1600000;            // 19159
    int* cnt_f = creg + 1619159;            // 19159
    int* off_g = creg + 1638318;            // 19159
    int* off_f = creg + 1657477;            // 19159 (end 1676636 < 6.4M)
    int* pers  = (int*)(ws + 12800000);
    int* rp_g  = pers;                      // 50001
    int* rp_f  = pers + 50001;              // 50001
    int* bb_g  = pers + 100002;             // 50
    int* bb_f  = pers + 100052;             // 50
    u16* adj_g = (u16*)(pers + 100102);     // 800000 u16
    u16* adj_f = (u16*)(pers + 500102);     // 800000 u16

    const int gblocks = (N_NODES + 63) / 64;   // 782
    const int nblk16  = (N_NODES + 15) / 16;   // 3125

    // CSR build, zero HBM atomics (LDS-only), both graphs per kernel
    p1_count_k<<<2 * NBLK, 256, 0, stream>>>(dst_g, dst_f, cnt_g, cnt_f,
                                             features, mask, norm_g, y);
    s1_scan_k<<<1, 1024, 0, stream>>>(cnt_g, off_g, bb_g, cnt_f, off_f, bb_f);
    p2_part_k<<<2 * NBLK, 256, 0, stream>>>(src_g, dst_g, off_g, rec_g,
                                            src_f, dst_f, off_f, rec_f);
    p3_build_k<<<2 * NBUK, 1024, 0, stream>>>(rec_g, bb_g, rp_g, adj_g,
                                              rec_f, bb_f, rp_f, adj_f);

    // z = aggG(y)   [agg before the 64->128 expansion; linearity of segsum]
    agg64_k<<<nblk16, 256, 0, stream>>>(y, rp_g, adj_g, z);

    // t1 = relu((z@W1)*ng + b1)   (fp32; overwrites dead build scratch)
    gemm_k<64, 128, 0, 1, 0><<<gblocks, 256, 0, stream>>>(z, nullptr, W1, norm_g,
                                                          b1, (void*)t1, N_NODES);
    // hb0 = (t1@wh)*ng   (fp16 out)
    gemm_k<128, 64, 0, 2, 1><<<gblocks, 256, 0, stream>>>(t1, nullptr, wh, norm_g,
                                                          nullptr, (void*)hb0, N_NODES);
    // sb0 = ((features*mask)@ws)*nf   (fp16 out)
    gemm_k<64, 64, 1, 2, 1><<<gblocks, 256, 0, stream>>>(features, mask, wsw, norm_f,
                                                         nullptr, (void*)sb0, N_NODES);

    // out = sigmoid(aggG(hb0)*ng + bh + aggF(sb0)*nf + bs)
    final2_k<<<nblk16, 256, 0, stream>>>(hb0, sb0, rp_g, adj_g, rp_f, adj_f,
                                         norm_g, norm_f, bh, bs, out);
}

// Round 9
// 247.507 us; speedup vs baseline: 11.6223x; 1.1886x over previous
//
#include <hip/hip_runtime.h>
#include <hip/hip_fp16.h>

#define N_NODES 50000
#define N_EDGES 800000
#define IN_F 64
#define H_F 128
#define NBUK 49          // node buckets of 1024: bucket = dst >> 10
#define EPB 2048         // edges per block in part_k
#define NBLK 391         // ceil(N_EDGES / EPB)
#define CAP 24576        // fixed per-bucket record capacity (mean 16384, +64 sigma)

typedef unsigned short u16;
typedef unsigned int u32;

static __device__ __forceinline__ float4 ld4(const float* p) {
    return *reinterpret_cast<const float4*>(p);
}
static __device__ __forceinline__ void st4(float* p, float4 v) {
    *reinterpret_cast<float4*>(p) = v;
}
// pack float4 -> 4 fp16 (8 B store)
static __device__ __forceinline__ void st_h4(__half* p, float4 v) {
    union { __half h[4]; uint2 u; } pk;
    pk.h[0] = __float2half_rn(v.x);
    pk.h[1] = __float2half_rn(v.y);
    pk.h[2] = __float2half_rn(v.z);
    pk.h[3] = __float2half_rn(v.w);
    *reinterpret_cast<uint2*>(p) = pk.u;
}
// acc(8 floats in two float4) += 8 halfs packed in uint4
static __device__ __forceinline__ void add_h8(float4& a, float4& b, uint4 r) {
    __half2* p = reinterpret_cast<__half2*>(&r);
    float2 f0 = __half22float2(p[0]);
    float2 f1 = __half22float2(p[1]);
    float2 f2 = __half22float2(p[2]);
    float2 f3 = __half22float2(p[3]);
    a.x += f0.x; a.y += f0.y; a.z += f1.x; a.w += f1.y;
    b.x += f2.x; b.y += f2.y; b.z += f3.x; b.w += f3.y;
}

// ---------- part_k: single-pass bucket partition (both graphs) + fused y = f*m*ng
// Per block: LDS hist of its 2048 edges -> one global atomicAdd per touched bucket
// (space reservation; order within bucket irrelevant) -> LDS-cursor placement.
__global__ __launch_bounds__(256) void part_k(
    const int* __restrict__ src_g, const int* __restrict__ dst_g, u32* __restrict__ rec_g,
    const int* __restrict__ src_f, const int* __restrict__ dst_f, u32* __restrict__ rec_f,
    int* __restrict__ bukcur,
    const float* __restrict__ f, const float* __restrict__ m,
    const float* __restrict__ ng, __half* __restrict__ y)
{
    __shared__ int c[NBUK];
    __shared__ int base[NBUK];
    const int tid = threadIdx.x;
    const int graph = blockIdx.x >= NBLK;
    const int blk = blockIdx.x - graph * NBLK;
    const int* src = graph ? src_f : src_g;
    const int* dst = graph ? dst_f : dst_g;
    u32* rec = graph ? rec_f : rec_g;
    int* cur = bukcur + graph * NBUK;

    if (tid < NBUK) c[tid] = 0;
    __syncthreads();
    const int e0 = blk * EPB;
    const int e1 = min(e0 + EPB, N_EDGES);

    u32 r_[8];
    bool v_[8];
#pragma unroll
    for (int j = 0; j < 8; ++j) {
        int e = e0 + tid + j * 256;
        v_[j] = (e < e1);
        int d = 0, s = 0;
        if (v_[j]) { d = dst[e]; s = src[e]; }
        r_[j] = ((u32)s << 16) | (u32)d;
        if (v_[j]) atomicAdd(&c[d >> 10], 1);
    }
    __syncthreads();
    if (tid < NBUK) base[tid] = atomicAdd(&cur[tid], c[tid]);
    __syncthreads();
    if (tid < NBUK) c[tid] = 0;                   // reuse as local cursor
    __syncthreads();
#pragma unroll
    for (int j = 0; j < 8; ++j) {
        if (v_[j]) {
            u32 r = r_[j];
            int b = (int)((r & 0xFFFFu) >> 10);
            int p = base[b] + atomicAdd(&c[b], 1);
            if (p < CAP) rec[b * CAP + p] = r;    // guard: drop on (impossible) overflow
        }
    }
    // fused: y = features * mask * ng, stored fp16
    for (int i = blockIdx.x * 256 + tid; i < N_NODES * (IN_F / 4);
         i += gridDim.x * 256) {
        int n = i >> 4;
        float s = ng[n];
        float4 a = ld4(f + 4 * i);
        float4 b = ld4(m + 4 * i);
        float4 r;
        r.x = a.x * b.x * s; r.y = a.y * b.y * s;
        r.z = a.z * b.z * s; r.w = a.w * b.w * s;
        st_h4(y + 4 * i, r);
    }
}

// ---------- P3: per-bucket LDS hist + scan -> rps/rpe; LDS-cursor scatter -> adj
__global__ __launch_bounds__(1024) void p3_build_k(
    const u32* __restrict__ rec_g, int* __restrict__ rps_g, int* __restrict__ rpe_g,
    u16* __restrict__ adj_g,
    const u32* __restrict__ rec_f, int* __restrict__ rps_f, int* __restrict__ rpe_f,
    u16* __restrict__ adj_f,
    const int* __restrict__ bukcur)
{
    __shared__ int hist[1024];
    __shared__ int tmp[1024];
    const int tid = threadIdx.x;
    const int graph = blockIdx.x >= NBUK;
    const int b = blockIdx.x - graph * NBUK;
    const u32* rec = graph ? rec_f : rec_g;
    int* rps = graph ? rps_f : rps_g;
    int* rpe = graph ? rpe_f : rpe_g;
    u16* adj = graph ? adj_f : adj_g;
    const int e_base = b * CAP;
    const int e_cnt  = min(bukcur[graph * NBUK + b], CAP);

    hist[tid] = 0;
    __syncthreads();
    for (int i = tid; i < e_cnt; i += 1024)
        atomicAdd(&hist[rec[e_base + i] & 1023], 1);
    __syncthreads();
    const int v = hist[tid];
    tmp[tid] = v;
    __syncthreads();
    for (int o = 1; o < 1024; o <<= 1) {
        int t = (tid >= o) ? tmp[tid - o] : 0;
        __syncthreads();
        tmp[tid] += t;
        __syncthreads();
    }
    const int incl = tmp[tid];
    const int excl = incl - v;
    const int n = (b << 10) + tid;
    if (n < N_NODES) {
        rps[n] = e_base + excl;
        rpe[n] = e_base + incl;
    }
    hist[tid] = excl;                             // becomes cursor
    __syncthreads();
    for (int i = tid; i < e_cnt; i += 1024) {
        u32 r = rec[e_base + i];
        int p = atomicAdd(&hist[r & 1023], 1);
        adj[e_base + p] = (u16)(r >> 16);         // single CU -> L2-local writes
    }
}

// ---------- CSR row gather-sum, 8-lane group, half8 (16 B uint4) per lane ----------
// Lane fl (0..7) accumulates features [8*fl .. 8*fl+7]; 8 lanes cover a 128 B row.
static __device__ __forceinline__ void csr_row_sum_h8(
        const __half* __restrict__ tbl, const u16* __restrict__ adj,
        int e, int e1, int off, float4& A, float4& B) {
    for (; e + 4 <= e1; e += 4) {
        int s0 = adj[e], s1 = adj[e + 1], s2 = adj[e + 2], s3 = adj[e + 3];
        uint4 r0 = *reinterpret_cast<const uint4*>(tbl + (s0 << 6) + off);
        uint4 r1 = *reinterpret_cast<const uint4*>(tbl + (s1 << 6) + off);
        uint4 r2 = *reinterpret_cast<const uint4*>(tbl + (s2 << 6) + off);
        uint4 r3 = *reinterpret_cast<const uint4*>(tbl + (s3 << 6) + off);
        add_h8(A, B, r0); add_h8(A, B, r1); add_h8(A, B, r2); add_h8(A, B, r3);
    }
    for (; e < e1; ++e) {
        uint4 r = *reinterpret_cast<const uint4*>(tbl + (adj[e] << 6) + off);
        add_h8(A, B, r);
    }
}

// ---------- agg64: z[n] (fp32) = sum_{src in N(n)} y16[src]; 32 nodes/block ----------
__global__ __launch_bounds__(256) void agg64_k(const __half* __restrict__ tbl,
        const int* __restrict__ rps, const int* __restrict__ rpe,
        const u16* __restrict__ adj, float* __restrict__ out) {
    const int tid = threadIdx.x;
    const int fl = tid & 7;
    const int n  = blockIdx.x * 32 + (tid >> 3);
    if (n >= N_NODES) return;
    const int off = fl << 3;
    float4 A = make_float4(0.f, 0.f, 0.f, 0.f);
    float4 B = make_float4(0.f, 0.f, 0.f, 0.f);
    csr_row_sum_h8(tbl, adj, rps[n], rpe[n], off, A, B);
    st4(out + (n << 6) + off, A);
    st4(out + (n << 6) + off + 4, B);
}

// ---------- tiled fp32 GEMM ----------
// out[n][c] = EPI( sum_k A'[n][k] * W[k][c] )
// SMODE 0: A' = A   SMODE 1: A' = A * A2
// EPI 1: relu(acc*rs[n] + bias[c]) -> fp32 out   EPI 2: acc*rs[n] -> out (fp16 if OUT16)
template<int K, int N, int SMODE, int EPI, int OUT16>
__global__ __launch_bounds__(256) void gemm_k(
    const float* __restrict__ A, const float* __restrict__ A2,
    const float* __restrict__ W, const float* __restrict__ rs,
    const float* __restrict__ bias, void* __restrict__ outv, int M)
{
    constexpr int CPT = N / 16;
    constexpr int AS  = K + 1;
    constexpr int KQ  = K / 4;
    __shared__ __align__(16) float Wl[K * N];
    __shared__ __align__(16) float Al[64 * AS];

    const int tid = threadIdx.x;
    const int n0  = blockIdx.x << 6;

    for (int i = tid; i < K * N / 4; i += 256) st4(&Wl[4 * i], ld4(W + 4 * i));
    for (int i4 = tid; i4 < 64 * KQ; i4 += 256) {
        int n  = i4 / KQ;
        int k4 = (i4 & (KQ - 1)) << 2;
        int gn = n0 + n;
        float4 v = make_float4(0.f, 0.f, 0.f, 0.f);
        if (gn < M) {
            v = ld4(A + gn * K + k4);
            if (SMODE == 1) {
                float4 m4 = ld4(A2 + gn * K + k4);
                v.x *= m4.x; v.y *= m4.y; v.z *= m4.z; v.w *= m4.w;
            }
        }
        float* p = &Al[n * AS + k4];
        p[0] = v.x; p[1] = v.y; p[2] = v.z; p[3] = v.w;
    }
    __syncthreads();

    const int tr = tid & 15;
    const int tc = tid >> 4;

    float acc[4][CPT];
#pragma unroll
    for (int i = 0; i < 4; ++i)
#pragma unroll
        for (int j = 0; j < CPT; ++j) acc[i][j] = 0.f;

#pragma unroll 4
    for (int k = 0; k < K; ++k) {
        float a0 = Al[(4 * tr + 0) * AS + k];
        float a1 = Al[(4 * tr + 1) * AS + k];
        float a2 = Al[(4 * tr + 2) * AS + k];
        float a3 = Al[(4 * tr + 3) * AS + k];
#pragma unroll
        for (int jq = 0; jq < CPT / 4; ++jq) {
            float4 w = ld4(&Wl[k * N + tc * CPT + 4 * jq]);
            acc[0][4 * jq + 0] += a0 * w.x; acc[0][4 * jq + 1] += a0 * w.y;
            acc[0][4 * jq + 2] += a0 * w.z; acc[0][4 * jq + 3] += a0 * w.w;
            acc[1][4 * jq + 0] += a1 * w.x; acc[1][4 * jq + 1] += a1 * w.y;
            acc[1][4 * jq + 2] += a1 * w.z; acc[1][4 * jq + 3] += a1 * w.w;
            acc[2][4 * jq + 0] += a2 * w.x; acc[2][4 * jq + 1] += a2 * w.y;
            acc[2][4 * jq + 2] += a2 * w.z; acc[2][4 * jq + 3] += a2 * w.w;
            acc[3][4 * jq + 0] += a3 * w.x; acc[3][4 * jq + 1] += a3 * w.y;
            acc[3][4 * jq + 2] += a3 * w.z; acc[3][4 * jq + 3] += a3 * w.w;
        }
    }

#pragma unroll
    for (int i = 0; i < 4; ++i) {
        int gn = n0 + 4 * tr + i;
        if (gn >= M) continue;
        float s = rs[gn];
#pragma unroll
        for (int jq = 0; jq < CPT / 4; ++jq) {
            float4 o;
            if (EPI == 1) {
                float4 b4 = ld4(bias + tc * CPT + 4 * jq);
                o.x = fmaxf(fmaf(acc[i][4 * jq + 0], s, b4.x), 0.f);
                o.y = fmaxf(fmaf(acc[i][4 * jq + 1], s, b4.y), 0.f);
                o.z = fmaxf(fmaf(acc[i][4 * jq + 2], s, b4.z), 0.f);
                o.w = fmaxf(fmaf(acc[i][4 * jq + 3], s, b4.w), 0.f);
            } else {
                o.x = acc[i][4 * jq + 0] * s; o.y = acc[i][4 * jq + 1] * s;
                o.z = acc[i][4 * jq + 2] * s; o.w = acc[i][4 * jq + 3] * s;
            }
            if (OUT16) {
                st_h4((__half*)outv + gn * N + tc * CPT + 4 * jq, o);
            } else {
                st4((float*)outv + gn * N + tc * CPT + 4 * jq, o);
            }
        }
    }
}

// ---------- fused final: two fp16 CSR aggs + bias + sigmoid; 32 nodes/block ----------
__global__ __launch_bounds__(256) void final2_k(
    const __half* __restrict__ hb, const __half* __restrict__ sb,
    const int* __restrict__ rps_g, const int* __restrict__ rpe_g,
    const u16* __restrict__ adj_g,
    const int* __restrict__ rps_f, const int* __restrict__ rpe_f,
    const u16* __restrict__ adj_f,
    const float* __restrict__ ng, const float* __restrict__ nf,
    const float* __restrict__ bh, const float* __restrict__ bs,
    float* __restrict__ out)
{
    const int tid = threadIdx.x;
    const int fl = tid & 7;
    const int n  = blockIdx.x * 32 + (tid >> 3);
    if (n >= N_NODES) return;
    const int off = fl << 3;
    float4 Ag = make_float4(0.f, 0.f, 0.f, 0.f);
    float4 Bg = make_float4(0.f, 0.f, 0.f, 0.f);
    float4 Af = make_float4(0.f, 0.f, 0.f, 0.f);
    float4 Bf = make_float4(0.f, 0.f, 0.f, 0.f);
    csr_row_sum_h8(hb, adj_g, rps_g[n], rpe_g[n], off, Ag, Bg);
    csr_row_sum_h8(sb, adj_f, rps_f[n], rpe_f[n], off, Af, Bf);
    const float g = ng[n], f = nf[n];
    float4 b0 = ld4(bh + off), b1 = ld4(bh + off + 4);
    float4 s0 = ld4(bs + off), s1 = ld4(bs + off + 4);
    float4 o0, o1;
    float t;
    t = Ag.x * g + b0.x + Af.x * f + s0.x; o0.x = 1.f / (1.f + expf(-t));
    t = Ag.y * g + b0.y + Af.y * f + s0.y; o0.y = 1.f / (1.f + expf(-t));
    t = Ag.z * g + b0.z + Af.z * f + s0.z; o0.z = 1.f / (1.f + expf(-t));
    t = Ag.w * g + b0.w + Af.w * f + s0.w; o0.w = 1.f / (1.f + expf(-t));
    t = Bg.x * g + b1.x + Bf.x * f + s1.x; o1.x = 1.f / (1.f + expf(-t));
    t = Bg.y * g + b1.y + Bf.y * f + s1.y; o1.y = 1.f / (1.f + expf(-t));
    t = Bg.z * g + b1.z + Bf.z * f + s1.z; o1.z = 1.f / (1.f + expf(-t));
    t = Bg.w * g + b1.w + Bf.w * f + s1.w; o1.w = 1.f / (1.f + expf(-t));
    st4(out + (n << 6) + off, o0);
    st4(out + (n << 6) + off + 4, o1);
}

extern "C" void kernel_launch(void* const* d_in, const int* in_sizes, int n_in,
                              void* d_out, int out_size, void* d_ws, size_t ws_size,
                              hipStream_t stream) {
    const float* features = (const float*)d_in[0];
    const float* mask     = (const float*)d_in[1];
    const float* norm_g   = (const float*)d_in[2];
    const float* norm_f   = (const float*)d_in[3];
    const int*   src_g    = (const int*)d_in[4];
    const int*   dst_g    = (const int*)d_in[5];
    const int*   src_f    = (const int*)d_in[6];
    const int*   dst_f    = (const int*)d_in[7];
    const float* W1  = (const float*)d_in[8];
    const float* b1  = (const float*)d_in[9];
    const float* wh  = (const float*)d_in[10];
    const float* bh  = (const float*)d_in[11];
    const float* wsw = (const float*)d_in[12];
    const float* bs  = (const float*)d_in[13];
    float* out = (float*)d_out;
    float* ws  = (float*)d_ws;

    // ---- workspace layout (float-unit offsets, lifetime-aliased) ----
    //   [0    , 3.2M)  y (fp16)        dead after agg64 -> hb0 (fp16, gemm2 out)
    //   [3.2M , 6.4M)  z (fp32)        dead after gemm1 -> sb0 (fp16, gemm3 out)
    //   [6.4M ,12.8M)  rec_g/rec_f/bukcur (dead after P3) -> t1 (fp32, 6.4M floats)
    // persistent at [12.8M): rps/rpe x2 graphs, adj_g/adj_f (CAP-padded)
    __half* y   = (__half*)ws;
    float*  z   = ws + 3200000;
    float*  t1  = ws + 6400000;
    __half* hb0 = (__half*)ws;              // alias y
    __half* sb0 = (__half*)(ws + 3200000);  // alias z
    int* creg   = (int*)(ws + 6400000);     // build scratch (aliases t1)
    u32* rec_g  = (u32*)creg;               // NBUK*CAP = 1204224
    u32* rec_f  = (u32*)(creg + NBUK * CAP);
    int* bukcur = creg + 2 * NBUK * CAP;    // 98 ints
    int* pers   = (int*)(ws + 12800000);
    int* rps_g  = pers;                     // 50000
    int* rpe_g  = pers + 50000;             // 50000
    int* rps_f  = pers + 100000;            // 50000
    int* rpe_f  = pers + 150000;            // 50000
    u16* adj_g  = (u16*)(pers + 200000);    // NBUK*CAP u16
    u16* adj_f  = adj_g + NBUK * CAP;       // NBUK*CAP u16

    const int gblocks = (N_NODES + 63) / 64;   // 782
    const int nblk32  = (N_NODES + 31) / 32;   // 1563

    // CSR build: reserve-based bucket partition (no global scan, no HBM value atomics)
    hipMemsetAsync(bukcur, 0, 2 * NBUK * sizeof(int), stream);
    part_k<<<2 * NBLK, 256, 0, stream>>>(src_g, dst_g, rec_g,
                                         src_f, dst_f, rec_f, bukcur,
                                         features, mask, norm_g, y);
    p3_build_k<<<2 * NBUK, 1024, 0, stream>>>(rec_g, rps_g, rpe_g, adj_g,
                                              rec_f, rps_f, rpe_f, adj_f, bukcur);

    // z = aggG(y)   [agg before the 64->128 expansion; linearity of segsum]
    agg64_k<<<nblk32, 256, 0, stream>>>(y, rps_g, rpe_g, adj_g, z);

    // t1 = relu((z@W1)*ng + b1)   (fp32; overwrites dead build scratch)
    gemm_k<64, 128, 0, 1, 0><<<gblocks, 256, 0, stream>>>(z, nullptr, W1, norm_g,
                                                          b1, (void*)t1, N_NODES);
    // hb0 = (t1@wh)*ng   (fp16 out)
    gemm_k<128, 64, 0, 2, 1><<<gblocks, 256, 0, stream>>>(t1, nullptr, wh, norm_g,
                                                          nullptr, (void*)hb0, N_NODES);
    // sb0 = ((features*mask)@ws)*nf   (fp16 out)
    gemm_k<64, 64, 1, 2, 1><<<gblocks, 256, 0, stream>>>(features, mask, wsw, norm_f,
                                                         nullptr, (void*)sb0, N_NODES);

    // out = sigmoid(aggG(hb0)*ng + bh + aggF(sb0)*nf + bs)
    final2_k<<<nblk32, 256, 0, stream>>>(hb0, sb0, rps_g, rpe_g, adj_g,
                                         rps_f, rpe_f, adj_f,
                                         norm_g, norm_f, bh, bs, out);
}